// Round 1
// baseline (532.347 us; speedup 1.0000x reference)
//
#include <hip/hip_runtime.h>

#define DEVINL __device__ __forceinline__

DEVINL float wave_sum(float v) {
  #pragma unroll
  for (int m = 32; m; m >>= 1) v += __shfl_xor(v, m, 64);
  return v;
}
DEVINL float wave_max(float v) {
  #pragma unroll
  for (int m = 32; m; m >>= 1) v = fmaxf(v, __shfl_xor(v, m, 64));
  return v;
}

#if defined(__has_builtin)
#if __has_builtin(__builtin_amdgcn_sdot4)
#define HAS_SDOT4 1
#endif
#endif

DEVINL int dot4(unsigned a, unsigned b, int c) {
#ifdef HAS_SDOT4
  return __builtin_amdgcn_sdot4((int)a, (int)b, c, false);
#else
  #pragma unroll
  for (int i = 0; i < 4; ++i) {
    int ai = (int)(a << (24 - 8 * i)) >> 24;
    int bi = (int)(b << (24 - 8 * i)) >> 24;
    c += ai * bi;
  }
  return c;
#endif
}

DEVINL unsigned packq4(float a, float b, float c, float d, float scale) {
  int ia = (int)fminf(fmaxf(rintf(a * scale), -1.f), 1.f);
  int ib = (int)fminf(fmaxf(rintf(b * scale), -1.f), 1.f);
  int ic = (int)fminf(fmaxf(rintf(c * scale), -1.f), 1.f);
  int id = (int)fminf(fmaxf(rintf(d * scale), -1.f), 1.f);
  return (unsigned)(ia & 255) | ((unsigned)(ib & 255) << 8) |
         ((unsigned)(ic & 255) << 16) | ((unsigned)(id & 255) << 24);
}

// ---------------- kernel 0: weight absmean + ternary pack ----------------
__global__ __launch_bounds__(256) void k_prep(
    const float* __restrict__ w1, const float* __restrict__ w2,
    float* __restrict__ scales, unsigned* __restrict__ u1p,
    unsigned* __restrict__ u2p) {
  __shared__ double red[4];
  __shared__ float mclip_s;
  const int tid = threadIdx.x;
  const float* w = (blockIdx.x == 0) ? w1 : w2;

  double s = 0.0;
  for (int e = tid; e < 16384; e += 256) s += (double)fabsf(w[e]);
  #pragma unroll
  for (int m = 32; m; m >>= 1) s += __shfl_xor(s, m, 64);
  if ((tid & 63) == 0) red[tid >> 6] = s;
  __syncthreads();
  if (tid == 0) {
    double tot = red[0] + red[1] + red[2] + red[3];
    float mc = fmaxf((float)(tot / 16384.0), 1e-5f);
    scales[blockIdx.x] = mc;
    mclip_s = mc;
  }
  __syncthreads();
  const float scale = 1.0f / mclip_s;

  if (blockIdx.x == 0) {
    // u1p[g*256 + o] packs w1[o][4g..4g+3], ternary int8
    for (int e = tid; e < 4096; e += 256) {
      int o = e & 255, g = e >> 8;
      float4 v = *(const float4*)(w1 + o * 64 + g * 4);
      u1p[g * 256 + o] = packq4(v.x, v.y, v.z, v.w, scale);
    }
  } else {
    // u2p[oc*64 + g] packs w2[oc][4g..4g+3]
    for (int e = tid; e < 4096; e += 256) {
      int g = e & 63, oc = e >> 6;
      float4 v = *(const float4*)(w2 + oc * 256 + g * 4);
      u2p[oc * 64 + g] = packq4(v.x, v.y, v.z, v.w, scale);
    }
  }
}

// ---------------- kernel 1: fused depthwise 3x3 + pointwise 1x1 ----------------
__global__ __launch_bounds__(256) void k_conv(
    const float* __restrict__ x, const float* __restrict__ dww,
    const float* __restrict__ dwb, const float* __restrict__ pww,
    const float* __restrict__ pwb, float* __restrict__ hout) {
  __shared__ float dws[64 * 65];   // [c][px]
  __shared__ float pwt[64 * 68];   // [c][o] transposed pw weights
  __shared__ float dww_s[576];
  __shared__ float dwb_s[64], pwb_s[64];

  const int tid = threadIdx.x;
  const int x0 = blockIdx.x * 64, y = blockIdx.y, bz = blockIdx.z;

  for (int e = tid; e < 4096; e += 256) {
    int c = e & 63, o = e >> 6;
    pwt[c * 68 + o] = pww[o * 64 + c];
  }
  for (int e = tid; e < 576; e += 256) dww_s[e] = dww[e];
  if (tid < 64) { dwb_s[tid] = dwb[tid]; pwb_s[tid] = pwb[tid]; }
  __syncthreads();

  const int px = tid & 63, grp = tid >> 6;
  const int gx = x0 + px;
  for (int c = grp; c < 64; c += 4) {
    const float* xc = x + (((size_t)bz * 64 + c) << 14);
    float acc = dwb_s[c];
    #pragma unroll
    for (int dy = 0; dy < 3; ++dy) {
      int iy = y + dy - 1;
      if ((unsigned)iy < 128u) {
        const float* row = xc + iy * 128;
        #pragma unroll
        for (int dx = 0; dx < 3; ++dx) {
          int ix = gx + dx - 1;
          if ((unsigned)ix < 128u)
            acc = fmaf(row[ix], dww_s[c * 9 + dy * 3 + dx], acc);
        }
      }
    }
    dws[c * 65 + px] = acc;
  }
  __syncthreads();

  // pointwise: thread handles outputs o0..o0+15 for pixel px
  const int o0 = grp * 16;
  float acc[16];
  #pragma unroll
  for (int m = 0; m < 16; ++m) acc[m] = pwb_s[o0 + m];
  for (int c = 0; c < 64; ++c) {
    float dv = dws[c * 65 + px];
    #pragma unroll
    for (int mm = 0; mm < 4; ++mm) {
      float4 wv = *(const float4*)&pwt[c * 68 + o0 + mm * 4];
      acc[mm * 4 + 0] = fmaf(dv, wv.x, acc[mm * 4 + 0]);
      acc[mm * 4 + 1] = fmaf(dv, wv.y, acc[mm * 4 + 1]);
      acc[mm * 4 + 2] = fmaf(dv, wv.z, acc[mm * 4 + 2]);
      acc[mm * 4 + 3] = fmaf(dv, wv.w, acc[mm * 4 + 3]);
    }
  }
  float* outp = hout + (((size_t)bz * 64) << 14) + (size_t)y * 128 + x0 + px;
  #pragma unroll
  for (int m = 0; m < 16; ++m)
    outp[((size_t)(o0 + m)) << 14] = acc[m];
}

// ---------------- kernel 2: LN + BitFF (int8 exact) + residual ----------------
__global__ __launch_bounds__(256) void k_ffn(
    const float* __restrict__ lnw, const float* __restrict__ lnb,
    const float* __restrict__ b1, const float* __restrict__ b2,
    const float* __restrict__ scales, const unsigned* __restrict__ u1pg,
    const unsigned* __restrict__ u2pg, float* __restrict__ dout) {
  __shared__ unsigned u1p[16 * 256];   // [g][o] packed ternary, o=4*lane+j
  __shared__ unsigned u2pT[64 * 68];   // [oc][g] packed ternary
  __shared__ float hs[64 * 65];        // [c][px]
  __shared__ unsigned qx1[4 * 16];     // per-wave packed int8 activations (64)
  __shared__ unsigned qx2[4 * 64];     // per-wave packed int8 activations (256)
  __shared__ float lnw_s[64], lnb_s[64], b2_s[64], b1_s[256];

  const int tid = threadIdx.x;
  const int w = tid >> 6, lane = tid & 63;
  const int x0 = blockIdx.x * 64, y = blockIdx.y, bz = blockIdx.z;

  const float m1c = scales[0], m2c = scales[1];

  for (int e = tid; e < 4096; e += 256) u1p[e] = u1pg[e];
  for (int e = tid; e < 4096; e += 256) {
    int oc = e >> 6, g = e & 63;
    u2pT[oc * 68 + g] = u2pg[e];
  }
  if (tid < 64) { lnw_s[tid] = lnw[tid]; lnb_s[tid] = lnb[tid]; b2_s[tid] = b2[tid]; }
  b1_s[tid] = b1[tid];

  float* hbase = dout + (((size_t)bz * 64) << 14) + (size_t)y * 128 + x0;
  for (int k = 0; k < 16; ++k) {
    int c = w + k * 4;
    hs[c * 65 + lane] = hbase[((size_t)c << 14) + lane];
  }
  __syncthreads();

  const float inv64 = 1.0f / 64.0f;
  const float gk = 0.707106781186547524f;

  for (int t = 0; t < 16; ++t) {
    const int p = w * 16 + t;   // this wave's token (pixel) this iteration
    float v = hs[lane * 65 + p];
    // LayerNorm over channels (lane = channel)
    float mu = wave_sum(v) * inv64;
    float d = v - mu;
    float var = wave_sum(d * d) * inv64;
    float tn = d * (1.0f / sqrtf(var + 1e-5f)) * lnw_s[lane] + lnb_s[lane];
    // SimpleRMSNorm (dim 64) + int8 absmax quant
    float n1 = sqrtf(wave_sum(tn * tn));
    float xn = tn / fmaxf(n1, 1e-12f) * 8.0f;
    float amax = wave_max(fabsf(xn));
    float sx1 = 127.0f / fmaxf(amax, 1e-5f);
    float qf = fminf(fmaxf(rintf(xn * sx1), -128.0f), 127.0f);
    ((signed char*)qx1)[w * 64 + lane] = (signed char)(int)qf;

    // BitLinear 1: o = 4*lane + j, exact int dot
    int a0 = 0, a1 = 0, a2 = 0, a3 = 0;
    const unsigned* qrow = &qx1[w * 16];
    #pragma unroll 4
    for (int g = 0; g < 16; ++g) {
      unsigned qv = qrow[g];
      uint4 wv = *(const uint4*)&u1p[g * 256 + 4 * lane];
      a0 = dot4(qv, wv.x, a0);
      a1 = dot4(qv, wv.y, a1);
      a2 = dot4(qv, wv.z, a2);
      a3 = dot4(qv, wv.w, a3);
    }
    float fsc = m1c / sx1;
    float4 bv = *(const float4*)&b1_s[4 * lane];
    float f0 = fmaf((float)a0, fsc, bv.x);
    float f1 = fmaf((float)a1, fsc, bv.y);
    float f2 = fmaf((float)a2, fsc, bv.z);
    float f3 = fmaf((float)a3, fsc, bv.w);
    // exact GELU
    f0 = 0.5f * f0 * (1.0f + erff(f0 * gk));
    f1 = 0.5f * f1 * (1.0f + erff(f1 * gk));
    f2 = 0.5f * f2 * (1.0f + erff(f2 * gk));
    f3 = 0.5f * f3 * (1.0f + erff(f3 * gk));
    // SimpleRMSNorm (dim 256) + quant
    float ss = wave_sum(f0 * f0 + f1 * f1 + f2 * f2 + f3 * f3);
    float n2 = fmaxf(sqrtf(ss), 1e-12f);
    float x0v = f0 / n2 * 16.0f;
    float x1v = f1 / n2 * 16.0f;
    float x2v = f2 / n2 * 16.0f;
    float x3v = f3 / n2 * 16.0f;
    float am = wave_max(fmaxf(fmaxf(fabsf(x0v), fabsf(x1v)),
                              fmaxf(fabsf(x2v), fabsf(x3v))));
    float sx2 = 127.0f / fmaxf(am, 1e-5f);
    int q0 = (int)fminf(fmaxf(rintf(x0v * sx2), -128.f), 127.f);
    int q1 = (int)fminf(fmaxf(rintf(x1v * sx2), -128.f), 127.f);
    int q2 = (int)fminf(fmaxf(rintf(x2v * sx2), -128.f), 127.f);
    int q3 = (int)fminf(fmaxf(rintf(x3v * sx2), -128.f), 127.f);
    qx2[w * 64 + lane] = (unsigned)(q0 & 255) | ((unsigned)(q1 & 255) << 8) |
                         ((unsigned)(q2 & 255) << 16) | ((unsigned)(q3 & 255) << 24);

    // BitLinear 2: lane = output channel
    int acc = 0;
    const unsigned* q2row = &qx2[w * 64];
    #pragma unroll 4
    for (int gb = 0; gb < 16; ++gb) {
      uint4 qv = *(const uint4*)&q2row[4 * gb];
      uint4 wv = *(const uint4*)&u2pT[lane * 68 + 4 * gb];
      acc = dot4(qv.x, wv.x, acc);
      acc = dot4(qv.y, wv.y, acc);
      acc = dot4(qv.z, wv.z, acc);
      acc = dot4(qv.w, wv.w, acc);
    }
    float fout = fmaf((float)acc, m2c / sx2, b2_s[lane]);
    hs[lane * 65 + p] += fout;  // residual: h + f
  }
  __syncthreads();

  for (int k = 0; k < 16; ++k) {
    int c = w * 16 + k;
    hbase[((size_t)c << 14) + lane] = hs[c * 65 + lane];
  }
}

extern "C" void kernel_launch(void* const* d_in, const int* in_sizes, int n_in,
                              void* d_out, int out_size, void* d_ws, size_t ws_size,
                              hipStream_t stream) {
  (void)in_sizes; (void)n_in; (void)out_size; (void)ws_size;
  const float* x   = (const float*)d_in[0];
  const float* dww = (const float*)d_in[1];
  const float* dwb = (const float*)d_in[2];
  const float* pww = (const float*)d_in[3];
  const float* pwb = (const float*)d_in[4];
  const float* lnw = (const float*)d_in[5];
  const float* lnb = (const float*)d_in[6];
  const float* w1  = (const float*)d_in[7];
  const float* b1  = (const float*)d_in[8];
  const float* w2  = (const float*)d_in[9];
  const float* b2  = (const float*)d_in[10];
  float* out = (float*)d_out;

  float* scales = (float*)d_ws;
  unsigned* u1p = (unsigned*)((char*)d_ws + 16);
  unsigned* u2p = u1p + 4096;

  hipLaunchKernelGGL(k_prep, dim3(2), dim3(256), 0, stream, w1, w2, scales, u1p, u2p);
  dim3 grid(2, 128, 16);
  hipLaunchKernelGGL(k_conv, grid, dim3(256), 0, stream, x, dww, dwb, pww, pwb, out);
  hipLaunchKernelGGL(k_ffn, grid, dim3(256), 0, stream, lnw, lnb, b1, b2, scales,
                     u1p, u2p, out);
}

// Round 3
// 332.179 us; speedup vs baseline: 1.6026x; 1.6026x over previous
//
#include <hip/hip_runtime.h>

#define DEVINL __device__ __forceinline__

typedef __attribute__((ext_vector_type(4))) int i32x4;

DEVINL float rcp_nr(float x) {
  float r = __builtin_amdgcn_rcpf(x);
  return r * (2.0f - x * r);
}
DEVINL float rsq_nr(float x) {
  float r = __builtin_amdgcn_rsqf(x);
  return r * (1.5f - 0.5f * x * r * r);
}
// exact-GELU via Abramowitz-Stegun 7.1.26 erf (|abs err| < 1.5e-7), branchless
DEVINL float gelu_f(float x) {
  float z = fabsf(x) * 0.7071067811865476f;
  float t = rcp_nr(fmaf(0.3275911f, z, 1.0f));
  float p = fmaf(1.061405429f, t, -1.453152027f);
  p = fmaf(p, t, 1.421413741f);
  p = fmaf(p, t, -0.284496736f);
  p = fmaf(p, t, 0.254829592f);
  p = p * t;
  float er = fmaf(-p, __expf(-z * z), 1.0f);
  er = copysignf(er, x);
  return 0.5f * x * (1.0f + er);
}

DEVINL unsigned packq4(float a, float b, float c, float d, float scale) {
  int ia = (int)fminf(fmaxf(rintf(a * scale), -1.f), 1.f);
  int ib = (int)fminf(fmaxf(rintf(b * scale), -1.f), 1.f);
  int ic = (int)fminf(fmaxf(rintf(c * scale), -1.f), 1.f);
  int id = (int)fminf(fmaxf(rintf(d * scale), -1.f), 1.f);
  return (unsigned)(ia & 255) | ((unsigned)(ib & 255) << 8) |
         ((unsigned)(ic & 255) << 16) | ((unsigned)(id & 255) << 24);
}

// ---------------- kernel 0: weight absmean + ternary pack (o-major bytes) ----
__global__ __launch_bounds__(256) void k_prep(
    const float* __restrict__ w1, const float* __restrict__ w2,
    float* __restrict__ scales, unsigned* __restrict__ u1p,
    unsigned* __restrict__ u2p) {
  __shared__ double red[4];
  __shared__ float mclip_s;
  const int tid = threadIdx.x;
  const float* w = (blockIdx.x == 0) ? w1 : w2;

  double s = 0.0;
  for (int e = tid; e < 16384; e += 256) s += (double)fabsf(w[e]);
  #pragma unroll
  for (int m = 32; m; m >>= 1) s += __shfl_xor(s, m, 64);
  if ((tid & 63) == 0) red[tid >> 6] = s;
  __syncthreads();
  if (tid == 0) {
    double tot = red[0] + red[1] + red[2] + red[3];
    float mc = fmaxf((float)(tot / 16384.0), 1e-5f);
    scales[blockIdx.x] = mc;
    mclip_s = mc;
  }
  __syncthreads();
  const float scale = 1.0f / mclip_s;

  if (blockIdx.x == 0) {
    // u1p[o*16 + d] packs ternary w1[o][4d..4d+3]
    for (int e = tid; e < 4096; e += 256) {
      float4 v = *(const float4*)(w1 + e * 4);
      u1p[e] = packq4(v.x, v.y, v.z, v.w, scale);
    }
  } else {
    // u2p[o*64 + d] packs ternary w2[o][4d..4d+3]
    for (int e = tid; e < 4096; e += 256) {
      float4 v = *(const float4*)(w2 + e * 4);
      u2p[e] = packq4(v.x, v.y, v.z, v.w, scale);
    }
  }
}

// ---------------- kernel 1: fused depthwise 3x3 + pointwise 1x1 (unchanged) --
__global__ __launch_bounds__(256) void k_conv(
    const float* __restrict__ x, const float* __restrict__ dww,
    const float* __restrict__ dwb, const float* __restrict__ pww,
    const float* __restrict__ pwb, float* __restrict__ hout) {
  __shared__ float dws[64 * 65];
  __shared__ float pwt[64 * 68];
  __shared__ float dww_s[576];
  __shared__ float dwb_s[64], pwb_s[64];

  const int tid = threadIdx.x;
  const int x0 = blockIdx.x * 64, y = blockIdx.y, bz = blockIdx.z;

  for (int e = tid; e < 4096; e += 256) {
    int c = e & 63, o = e >> 6;
    pwt[c * 68 + o] = pww[o * 64 + c];
  }
  for (int e = tid; e < 576; e += 256) dww_s[e] = dww[e];
  if (tid < 64) { dwb_s[tid] = dwb[tid]; pwb_s[tid] = pwb[tid]; }
  __syncthreads();

  const int px = tid & 63, grp = tid >> 6;
  const int gx = x0 + px;
  for (int c = grp; c < 64; c += 4) {
    const float* xc = x + (((size_t)bz * 64 + c) << 14);
    float acc = dwb_s[c];
    #pragma unroll
    for (int dy = 0; dy < 3; ++dy) {
      int iy = y + dy - 1;
      if ((unsigned)iy < 128u) {
        const float* row = xc + iy * 128;
        #pragma unroll
        for (int dx = 0; dx < 3; ++dx) {
          int ix = gx + dx - 1;
          if ((unsigned)ix < 128u)
            acc = fmaf(row[ix], dww_s[c * 9 + dy * 3 + dx], acc);
        }
      }
    }
    dws[c * 65 + px] = acc;
  }
  __syncthreads();

  const int o0 = grp * 16;
  float acc[16];
  #pragma unroll
  for (int m = 0; m < 16; ++m) acc[m] = pwb_s[o0 + m];
  for (int c = 0; c < 64; ++c) {
    float dv = dws[c * 65 + px];
    #pragma unroll
    for (int mm = 0; mm < 4; ++mm) {
      float4 wv = *(const float4*)&pwt[c * 68 + o0 + mm * 4];
      acc[mm * 4 + 0] = fmaf(dv, wv.x, acc[mm * 4 + 0]);
      acc[mm * 4 + 1] = fmaf(dv, wv.y, acc[mm * 4 + 1]);
      acc[mm * 4 + 2] = fmaf(dv, wv.z, acc[mm * 4 + 2]);
      acc[mm * 4 + 3] = fmaf(dv, wv.w, acc[mm * 4 + 3]);
    }
  }
  float* outp = hout + (((size_t)bz * 64) << 14) + (size_t)y * 128 + x0 + px;
  #pragma unroll
  for (int m = 0; m < 16; ++m)
    outp[((size_t)(o0 + m)) << 14] = acc[m];
}

// ---------------- kernel 2: LN + BitFF via i8 MFMA + residual ----------------
// Block = 256 threads (4 waves) handles one row = 128 tokens of one image.
// Phase N (lane=token): LN + rms1 + int8 quant, write qbuf[token][64B].
// Phase M (per wave, 2 tiles of 16 tokens): D1[o][t]=W1q*QX^T via MFMA,
//   GELU, rms2+quant (lane-local + 2 shfl), D2[o2][t]=W2q*QF^T, residual.
// NOTE: qf2 is written AND read as `unsigned` (same TBAA type, no barrier
// needed for wave-local LDS ordering). Mixed-type LDS (unsigned store /
// long long load) elsewhere is always separated by __syncthreads().
__global__ __launch_bounds__(256, 2) void k_ffn(
    const float* __restrict__ lnw, const float* __restrict__ lnb,
    const float* __restrict__ b1, const float* __restrict__ b2,
    const float* __restrict__ scales, const unsigned* __restrict__ u1p,
    const unsigned* __restrict__ u2p, float* __restrict__ dout) {
  __shared__ __align__(16) signed char w1p[256 * 72];   // [o][k] pad 72
  __shared__ __align__(16) signed char w2p[64 * 264];   // [o][k] pad 264
  __shared__ __align__(16) signed char qbuf[128 * 64];  // [tok][c]
  __shared__ __align__(16) unsigned qf2[4][16 * 66];    // per-wave [t][66 dw]
  __shared__ float redA[4][64], redB[4][64];
  __shared__ float tokscale[128];
  __shared__ float lnw_s[64], lnb_s[64], b2s[64], b1s[256];
  __shared__ float sc_s[2];

  const int tid = threadIdx.x;
  const int w = tid >> 6, lane = tid & 63;
  const int y = blockIdx.x, bz = blockIdx.y;
  const size_t gbase = ((size_t)bz * 64) << 14;

  // ---- LDS fill ----
  for (int e = tid; e < 4096; e += 256) {
    int o = e >> 4, d = e & 15;
    ((unsigned*)w1p)[o * 18 + d] = u1p[e];
  }
  for (int e = tid; e < 4096; e += 256) {
    int o = e >> 6, d = e & 63;
    ((unsigned*)w2p)[o * 66 + d] = u2p[e];
  }
  if (tid < 64) { lnw_s[tid] = lnw[tid]; lnb_s[tid] = lnb[tid]; b2s[tid] = b2[tid]; }
  b1s[tid] = b1[tid];
  if (tid < 2) sc_s[tid] = scales[tid];

  // ---- Phase N: lane = token, 32 channels per lane ----
  const int half = w >> 1, cpart = w & 1;
  const int tok = half * 64 + lane;
  const int c0 = cpart * 32;
  const int pixn = y * 128 + tok;

  float xv[32];
  float s1 = 0.f, q1 = 0.f;
  #pragma unroll
  for (int i = 0; i < 32; ++i) {
    float v = dout[gbase + (((size_t)(c0 + i)) << 14) + pixn];
    xv[i] = v;
    s1 += v;
    q1 = fmaf(v, v, q1);
  }
  redA[w][lane] = s1;
  redB[w][lane] = q1;
  __syncthreads();   // also covers LDS fill
  float S = redA[half * 2][lane] + redA[half * 2 + 1][lane];
  float Q = redB[half * 2][lane] + redB[half * 2 + 1][lane];
  __syncthreads();   // before red reuse

  const float mu = S * (1.f / 64.f);
  const float var = fmaxf(Q * (1.f / 64.f) - mu * mu, 0.f);
  const float istd = rsq_nr(var + 1e-5f);
  float s2 = 0.f, am = 0.f;
  #pragma unroll
  for (int i = 0; i < 32; ++i) {
    float tn = (xv[i] - mu) * istd * lnw_s[c0 + i] + lnb_s[c0 + i];
    xv[i] = tn;
    s2 = fmaf(tn, tn, s2);
    am = fmaxf(am, fabsf(tn));
  }
  redA[w][lane] = s2;
  redB[w][lane] = am;
  __syncthreads();
  float S2 = redA[half * 2][lane] + redA[half * 2 + 1][lane];
  float AM = fmaxf(redB[half * 2][lane], redB[half * 2 + 1][lane]);

  const float n1 = sqrtf(S2);
  const float inv1 = rcp_nr(fmaxf(n1, 1e-12f));
  const float axc1 = fmaxf(AM * 8.f * inv1, 1e-5f);
  const float sx1 = 127.f * rcp_nr(axc1);
  const float qs1 = 8.f * inv1 * sx1;
  if (cpart == 0) tokscale[tok] = sc_s[0] * axc1 * (1.f / 127.f);

  #pragma unroll
  for (int j = 0; j < 8; ++j) {
    int v0 = (int)fminf(fmaxf(rintf(xv[4 * j + 0] * qs1), -128.f), 127.f);
    int v1 = (int)fminf(fmaxf(rintf(xv[4 * j + 1] * qs1), -128.f), 127.f);
    int v2 = (int)fminf(fmaxf(rintf(xv[4 * j + 2] * qs1), -128.f), 127.f);
    int v3 = (int)fminf(fmaxf(rintf(xv[4 * j + 3] * qs1), -128.f), 127.f);
    unsigned pk = (unsigned)(v0 & 255) | ((unsigned)(v1 & 255) << 8) |
                  ((unsigned)(v2 & 255) << 16) | ((unsigned)(v3 & 255) << 24);
    ((unsigned*)qbuf)[tok * 16 + cpart * 8 + j] = pk;
  }
  __syncthreads();

  // ---- Phase M: per wave, tiles 2w and 2w+1 (16 tokens each) ----
  const int col = lane & 15, hi = lane >> 4;
  const float m2c = sc_s[1];
  unsigned* qf2w = qf2[w];

  for (int tl = 2 * w; tl <= 2 * w + 1; ++tl) {
    const int t0 = tl * 16;
    const int pix = y * 128 + t0 + col;

    // BitLinear1 (transposed): D1[o][t], A = w1 ternary rows, B = qx
    const signed char* qrow = &qbuf[(t0 + col) * 64];
    const long long bq0 = *(const long long*)&qrow[hi * 8];
    const long long bq1 = *(const long long*)&qrow[32 + hi * 8];
    i32x4 c1[16];
    #pragma unroll
    for (int n = 0; n < 16; ++n) {
      const signed char* arow = &w1p[(n * 16 + col) * 72 + hi * 8];
      long long a0 = *(const long long*)(arow);
      long long a1 = *(const long long*)(arow + 32);
      i32x4 cc = {0, 0, 0, 0};
      cc = __builtin_amdgcn_mfma_i32_16x16x32_i8(a0, bq0, cc, 0, 0, 0);
      cc = __builtin_amdgcn_mfma_i32_16x16x32_i8(a1, bq1, cc, 0, 0, 0);
      c1[n] = cc;
    }

    // dequant + bias + exact GELU; rms2/amax partials (lane-local 64 vals)
    const float fsc1 = tokscale[t0 + col];
    float g[16][4];
    float sum2 = 0.f, am2 = 0.f;
    #pragma unroll
    for (int n = 0; n < 16; ++n) {
      const float4 bb = *(const float4*)&b1s[n * 16 + hi * 4];
      #pragma unroll
      for (int r = 0; r < 4; ++r) {
        float f = (float)c1[n][r] * fsc1 + ((const float*)&bb)[r];
        float gg = gelu_f(f);
        g[n][r] = gg;
        sum2 = fmaf(gg, gg, sum2);
        am2 = fmaxf(am2, fabsf(gg));
      }
    }
    // combine across the 4 lanes holding token `col`
    sum2 += __shfl_xor(sum2, 16, 64);
    sum2 += __shfl_xor(sum2, 32, 64);
    am2 = fmaxf(am2, __shfl_xor(am2, 16, 64));
    am2 = fmaxf(am2, __shfl_xor(am2, 32, 64));

    const float n2 = sqrtf(sum2);
    const float inv2 = rcp_nr(fmaxf(n2, 1e-12f));
    const float axc2 = fmaxf(am2 * 16.f * inv2, 1e-5f);
    const float sx2 = 127.f * rcp_nr(axc2);
    const float qs2 = 16.f * inv2 * sx2;
    const float fsc2 = m2c * axc2 * (1.f / 127.f);

    // quantize intermediate: token-row dword d holds features 4d..4d+3
    #pragma unroll
    for (int n = 0; n < 16; ++n) {
      int q0 = (int)fminf(fmaxf(rintf(g[n][0] * qs2), -128.f), 127.f);
      int q1i = (int)fminf(fmaxf(rintf(g[n][1] * qs2), -128.f), 127.f);
      int q2 = (int)fminf(fmaxf(rintf(g[n][2] * qs2), -128.f), 127.f);
      int q3 = (int)fminf(fmaxf(rintf(g[n][3] * qs2), -128.f), 127.f);
      unsigned pk = (unsigned)(q0 & 255) | ((unsigned)(q1i & 255) << 8) |
                    ((unsigned)(q2 & 255) << 16) | ((unsigned)(q3 & 255) << 24);
      qf2w[col * 66 + n * 4 + hi] = pk;
    }

    // prefetch residual h while MFMA2 runs
    float hv[4][4];
    #pragma unroll
    for (int n2i = 0; n2i < 4; ++n2i)
      #pragma unroll
      for (int r = 0; r < 4; ++r)
        hv[n2i][r] =
            dout[gbase + (((size_t)(n2i * 16 + hi * 4 + r)) << 14) + pix];

    // BitLinear2 (transposed): D2[o2][t], K = 256 in 8 k-steps.
    // B-operand read as two `unsigned` loads (same type as the stores above
    // -> compiler must preserve order; wave-local LDS ops execute in order).
    i32x4 c2[4];
    #pragma unroll
    for (int n2i = 0; n2i < 4; ++n2i) c2[n2i] = (i32x4){0, 0, 0, 0};
    #pragma unroll
    for (int ks = 0; ks < 8; ++ks) {
      const unsigned* brow = &qf2w[col * 66 + ks * 8 + hi * 2];
      unsigned blo = brow[0], bhi = brow[1];
      const long long bfr =
          (long long)(((unsigned long long)bhi << 32) | (unsigned long long)blo);
      #pragma unroll
      for (int n2i = 0; n2i < 4; ++n2i) {
        const long long afr =
            *(const long long*)&w2p[(n2i * 16 + col) * 264 + ks * 32 + hi * 8];
        c2[n2i] = __builtin_amdgcn_mfma_i32_16x16x32_i8(afr, bfr, c2[n2i], 0, 0, 0);
      }
    }

    // epilogue: dequant + b2 + residual, store
    #pragma unroll
    for (int n2i = 0; n2i < 4; ++n2i) {
      const float4 bb = *(const float4*)&b2s[n2i * 16 + hi * 4];
      #pragma unroll
      for (int r = 0; r < 4; ++r) {
        float v = (float)c2[n2i][r] * fsc2 + ((const float*)&bb)[r] + hv[n2i][r];
        dout[gbase + (((size_t)(n2i * 16 + hi * 4 + r)) << 14) + pix] = v;
      }
    }
  }
}

extern "C" void kernel_launch(void* const* d_in, const int* in_sizes, int n_in,
                              void* d_out, int out_size, void* d_ws, size_t ws_size,
                              hipStream_t stream) {
  (void)in_sizes; (void)n_in; (void)out_size; (void)ws_size;
  const float* x   = (const float*)d_in[0];
  const float* dww = (const float*)d_in[1];
  const float* dwb = (const float*)d_in[2];
  const float* pww = (const float*)d_in[3];
  const float* pwb = (const float*)d_in[4];
  const float* lnw = (const float*)d_in[5];
  const float* lnb = (const float*)d_in[6];
  const float* w1  = (const float*)d_in[7];
  const float* b1  = (const float*)d_in[8];
  const float* w2  = (const float*)d_in[9];
  const float* b2  = (const float*)d_in[10];
  float* out = (float*)d_out;

  float* scales = (float*)d_ws;
  unsigned* u1p = (unsigned*)((char*)d_ws + 16);
  unsigned* u2p = u1p + 4096;

  hipLaunchKernelGGL(k_prep, dim3(2), dim3(256), 0, stream, w1, w2, scales, u1p, u2p);
  hipLaunchKernelGGL(k_conv, dim3(2, 128, 16), dim3(256), 0, stream,
                     x, dww, dwb, pww, pwb, out);
  hipLaunchKernelGGL(k_ffn, dim3(128, 16), dim3(256), 0, stream,
                     lnw, lnb, b1, b2, scales, u1p, u2p, out);
}

// Round 4
// 324.038 us; speedup vs baseline: 1.6429x; 1.0251x over previous
//
#include <hip/hip_runtime.h>

#define DEVINL __device__ __forceinline__

typedef __attribute__((ext_vector_type(4))) int i32x4;

DEVINL float rcp_nr(float x) {
  float r = __builtin_amdgcn_rcpf(x);
  return r * (2.0f - x * r);
}
DEVINL float rsq_nr(float x) {
  float r = __builtin_amdgcn_rsqf(x);
  return r * (1.5f - 0.5f * x * r * r);
}
// exact-GELU via Abramowitz-Stegun 7.1.26 erf (|abs err| < 1.5e-7), branchless
DEVINL float gelu_f(float x) {
  float z = fabsf(x) * 0.7071067811865476f;
  float t = rcp_nr(fmaf(0.3275911f, z, 1.0f));
  float p = fmaf(1.061405429f, t, -1.453152027f);
  p = fmaf(p, t, 1.421413741f);
  p = fmaf(p, t, -0.284496736f);
  p = fmaf(p, t, 0.254829592f);
  p = p * t;
  float er = fmaf(-p, __expf(-z * z), 1.0f);
  er = copysignf(er, x);
  return 0.5f * x * (1.0f + er);
}

DEVINL unsigned packq4(float a, float b, float c, float d, float scale) {
  int ia = (int)fminf(fmaxf(rintf(a * scale), -1.f), 1.f);
  int ib = (int)fminf(fmaxf(rintf(b * scale), -1.f), 1.f);
  int ic = (int)fminf(fmaxf(rintf(c * scale), -1.f), 1.f);
  int id = (int)fminf(fmaxf(rintf(d * scale), -1.f), 1.f);
  return (unsigned)(ia & 255) | ((unsigned)(ib & 255) << 8) |
         ((unsigned)(ic & 255) << 16) | ((unsigned)(id & 255) << 24);
}

DEVINL long long mk64(unsigned lo, unsigned hi) {
  return (long long)(((unsigned long long)hi << 32) | (unsigned long long)lo);
}

// ---------------- kernel 0: weight absmean + ternary pack (o-major bytes) ----
__global__ __launch_bounds__(256) void k_prep(
    const float* __restrict__ w1, const float* __restrict__ w2,
    float* __restrict__ scales, unsigned* __restrict__ u1p,
    unsigned* __restrict__ u2p) {
  __shared__ double red[4];
  __shared__ float mclip_s;
  const int tid = threadIdx.x;
  const float* w = (blockIdx.x == 0) ? w1 : w2;

  double s = 0.0;
  for (int e = tid; e < 16384; e += 256) s += (double)fabsf(w[e]);
  #pragma unroll
  for (int m = 32; m; m >>= 1) s += __shfl_xor(s, m, 64);
  if ((tid & 63) == 0) red[tid >> 6] = s;
  __syncthreads();
  if (tid == 0) {
    double tot = red[0] + red[1] + red[2] + red[3];
    float mc = fmaxf((float)(tot / 16384.0), 1e-5f);
    scales[blockIdx.x] = mc;
    mclip_s = mc;
  }
  __syncthreads();
  const float scale = 1.0f / mclip_s;

  if (blockIdx.x == 0) {
    for (int e = tid; e < 4096; e += 256) {
      float4 v = *(const float4*)(w1 + e * 4);
      u1p[e] = packq4(v.x, v.y, v.z, v.w, scale);
    }
  } else {
    for (int e = tid; e < 4096; e += 256) {
      float4 v = *(const float4*)(w2 + e * 4);
      u2p[e] = packq4(v.x, v.y, v.z, v.w, scale);
    }
  }
}

// ---------------- kernel 1: depthwise 3x3 stencil (streaming) ----------------
// Writes dw result into d_out as an intermediate; k_fused consumes exactly the
// rows it later overwrites (no cross-block hazard).
__global__ __launch_bounds__(256) void k_dw(
    const float* __restrict__ x, const float* __restrict__ dww,
    const float* __restrict__ dwb, float* __restrict__ dout) {
  const int tid = threadIdx.x;
  const int px = tid & 127, ry = tid >> 7;
  const int y = blockIdx.x * 2 + ry;
  const int c = blockIdx.y;
  const int bz = blockIdx.z;
  const float* xc = x + (((size_t)bz * 64 + c) << 14);

  float wv[9];
  #pragma unroll
  for (int i = 0; i < 9; ++i) wv[i] = dww[c * 9 + i];
  float acc = dwb[c];
  #pragma unroll
  for (int dy = 0; dy < 3; ++dy) {
    int iy = y + dy - 1;
    if ((unsigned)iy < 128u) {
      const float* row = xc + (iy << 7);
      #pragma unroll
      for (int dx = 0; dx < 3; ++dx) {
        int ix = px + dx - 1;
        if ((unsigned)ix < 128u) acc = fmaf(row[ix], wv[dy * 3 + dx], acc);
      }
    }
  }
  dout[(((size_t)bz * 64 + c) << 14) + (y << 7) + px] = acc;
}

// ---------------- kernel 2: pw 1x1 + LN + BitFF(i8 MFMA) + residual ---------
// Block = 256 threads (4 waves) = one row y of one image (128 tokens).
// Unified mapping: thread (col = lane&15, hi = lane>>4) of wave w owns
//   token 32w + 16*tl + col and channels {16*n2 + 4*hi + r}  (MFMA C/D layout).
// Phases: [stage weights -> barrier] P: pw GEMM, h in regs (dws slice staged
// per-wave in LDS union) -> [barrier = TBAA fence] per tile: N (LN+rms1+quant,
// shfl-reduce over hi), M (BL1 MFMA -> GELU -> rms2+quant -> BL2 MFMA ->
// +h residual -> store). After the fence everything is wave-local.
__global__ __launch_bounds__(256, 2) void k_fused(
    const float* __restrict__ pww, const float* __restrict__ pwb,
    const float* __restrict__ lnw, const float* __restrict__ lnb,
    const float* __restrict__ b1, const float* __restrict__ b2,
    const float* __restrict__ scales, const unsigned* __restrict__ u1p,
    const unsigned* __restrict__ u2p, float* __restrict__ dout) {
  __shared__ float pwt[64 * 68];                      // [k][o] transposed pw
  __shared__ __align__(16) signed char w2p[64 * 264]; // [o][k] pad 264
  __shared__ __align__(16) char uni[4][6272];         // per-wave union
  __shared__ float pwb_s[64], lnw_s[64], lnb_s[64], b2s[64];
  __shared__ float b1s[256];
  __shared__ float sc_s[2];

  const int tid = threadIdx.x;
  const int w = tid >> 6, lane = tid & 63;
  const int col = lane & 15, hi = lane >> 4;
  const int y = blockIdx.x, bz = blockIdx.y;
  const size_t gbase = ((size_t)bz * 64) << 14;
  const int rowoff = y * 128;

  // ---- stage weights ----
  for (int e = tid; e < 4096; e += 256) {
    int k = e & 63, o = e >> 6;
    pwt[k * 68 + o] = pww[o * 64 + k];
  }
  for (int e = tid; e < 4096; e += 256) {
    int o = e >> 6, d = e & 63;
    ((unsigned*)w2p)[o * 66 + d] = u2p[e];
  }
  if (tid < 64) {
    pwb_s[tid] = pwb[tid]; lnw_s[tid] = lnw[tid];
    lnb_s[tid] = lnb[tid]; b2s[tid] = b2[tid];
  }
  b1s[tid] = b1[tid];
  if (tid < 2) sc_s[tid] = scales[tid];

  // w1 ternary A-fragments -> registers (shared by both tiles)
  long long w1a0[16], w1a1[16];
  #pragma unroll
  for (int n = 0; n < 16; ++n) {
    const unsigned* q = &u1p[(n * 16 + col) * 16];
    uint2 lo = *(const uint2*)&q[2 * hi];
    uint2 hh = *(const uint2*)&q[8 + 2 * hi];
    w1a0[n] = mk64(lo.x, lo.y);
    w1a1[n] = mk64(hh.x, hh.y);
  }
  __syncthreads();  // weights visible to all waves

  // ---- Phase P: pointwise GEMM, h in registers ----
  float* dwsl = (float*)(&uni[w][0]);  // [32 k][33 px] chunk, wave-local
  float hacc[2][4][4];
  #pragma unroll
  for (int n2 = 0; n2 < 4; ++n2) {
    float4 pb = *(const float4*)&pwb_s[n2 * 16 + 4 * hi];
    #pragma unroll
    for (int r = 0; r < 4; ++r) {
      hacc[0][n2][r] = ((const float*)&pb)[r];
      hacc[1][n2][r] = ((const float*)&pb)[r];
    }
  }
  #pragma unroll
  for (int ch = 0; ch < 2; ++ch) {
    // stage dw chunk [32 k][32 px] for this wave's 32 tokens
    #pragma unroll
    for (int i = 0; i < 16; ++i) {
      int k = i * 2 + (lane >> 5);
      int p32 = lane & 31;
      dwsl[k * 33 + p32] =
          dout[gbase + (((size_t)(ch * 32 + k)) << 14) + rowoff + w * 32 + p32];
    }
    #pragma unroll 4
    for (int kk = 0; kk < 32; ++kk) {
      float4 wv[4];
      #pragma unroll
      for (int n2 = 0; n2 < 4; ++n2)
        wv[n2] = *(const float4*)&pwt[(ch * 32 + kk) * 68 + n2 * 16 + 4 * hi];
      #pragma unroll
      for (int tl = 0; tl < 2; ++tl) {
        float dv = dwsl[kk * 33 + tl * 16 + col];
        #pragma unroll
        for (int n2 = 0; n2 < 4; ++n2) {
          #pragma unroll
          for (int r = 0; r < 4; ++r)
            hacc[tl][n2][r] = fmaf(dv, ((const float*)&wv[n2])[r], hacc[tl][n2][r]);
        }
      }
    }
  }
  __syncthreads();  // fence: float dws accesses vs unsigned wq/qf2 (TBAA)

  unsigned* wq = (unsigned*)(&uni[w][0]);      // [2 tl][16 tok][16 dw]
  unsigned* qf2w = (unsigned*)(&uni[w][2048]); // [16 tok][66 dw]
  const float sc0 = sc_s[0], m2c = sc_s[1];

  for (int tl = 0; tl < 2; ++tl) {
    const int t0 = w * 32 + tl * 16;

    // ---- Phase N: LayerNorm + rms1 + int8 quant (shfl over hi-group) ----
    float s1 = 0.f, q1 = 0.f;
    #pragma unroll
    for (int n2 = 0; n2 < 4; ++n2)
      #pragma unroll
      for (int r = 0; r < 4; ++r) {
        float v = hacc[tl][n2][r];
        s1 += v;
        q1 = fmaf(v, v, q1);
      }
    s1 += __shfl_xor(s1, 16, 64); s1 += __shfl_xor(s1, 32, 64);
    q1 += __shfl_xor(q1, 16, 64); q1 += __shfl_xor(q1, 32, 64);
    const float mu = s1 * (1.f / 64.f);
    const float var = fmaxf(q1 * (1.f / 64.f) - mu * mu, 0.f);
    const float istd = rsq_nr(var + 1e-5f);

    float tn[4][4];
    float s2 = 0.f, am = 0.f;
    #pragma unroll
    for (int n2 = 0; n2 < 4; ++n2) {
      float4 lw = *(const float4*)&lnw_s[n2 * 16 + 4 * hi];
      float4 lb = *(const float4*)&lnb_s[n2 * 16 + 4 * hi];
      #pragma unroll
      for (int r = 0; r < 4; ++r) {
        float t = (hacc[tl][n2][r] - mu) * istd * ((const float*)&lw)[r] +
                  ((const float*)&lb)[r];
        tn[n2][r] = t;
        s2 = fmaf(t, t, s2);
        am = fmaxf(am, fabsf(t));
      }
    }
    s2 += __shfl_xor(s2, 16, 64); s2 += __shfl_xor(s2, 32, 64);
    am = fmaxf(am, __shfl_xor(am, 16, 64));
    am = fmaxf(am, __shfl_xor(am, 32, 64));

    const float n1 = sqrtf(s2);
    const float inv1 = rcp_nr(fmaxf(n1, 1e-12f));
    const float axc1 = fmaxf(am * 8.f * inv1, 1e-5f);
    const float sx1 = 127.f * rcp_nr(axc1);
    const float qs1 = 8.f * inv1 * sx1;
    const float fsc1 = sc0 * axc1 * (1.f / 127.f);

    #pragma unroll
    for (int n2 = 0; n2 < 4; ++n2) {
      int v0 = (int)fminf(fmaxf(rintf(tn[n2][0] * qs1), -128.f), 127.f);
      int v1 = (int)fminf(fmaxf(rintf(tn[n2][1] * qs1), -128.f), 127.f);
      int v2 = (int)fminf(fmaxf(rintf(tn[n2][2] * qs1), -128.f), 127.f);
      int v3 = (int)fminf(fmaxf(rintf(tn[n2][3] * qs1), -128.f), 127.f);
      unsigned pk = (unsigned)(v0 & 255) | ((unsigned)(v1 & 255) << 8) |
                    ((unsigned)(v2 & 255) << 16) | ((unsigned)(v3 & 255) << 24);
      wq[tl * 256 + col * 16 + n2 * 4 + hi] = pk;  // dw d = features 4d..4d+3
    }

    // ---- Phase M: BitLinear1 (MFMA) ----
    const unsigned* wqt = &wq[tl * 256 + col * 16];
    unsigned bq00 = wqt[2 * hi], bq01 = wqt[2 * hi + 1];
    unsigned bq10 = wqt[8 + 2 * hi], bq11 = wqt[8 + 2 * hi + 1];
    const long long bq0 = mk64(bq00, bq01);
    const long long bq1 = mk64(bq10, bq11);

    i32x4 c1[16];
    #pragma unroll
    for (int n = 0; n < 16; ++n) {
      i32x4 cc = {0, 0, 0, 0};
      cc = __builtin_amdgcn_mfma_i32_16x16x32_i8(w1a0[n], bq0, cc, 0, 0, 0);
      cc = __builtin_amdgcn_mfma_i32_16x16x32_i8(w1a1[n], bq1, cc, 0, 0, 0);
      c1[n] = cc;
    }

    // dequant + bias + exact GELU; rms2/amax partials
    float g[16][4];
    float sum2 = 0.f, am2 = 0.f;
    #pragma unroll
    for (int n = 0; n < 16; ++n) {
      const float4 bb = *(const float4*)&b1s[n * 16 + hi * 4];
      #pragma unroll
      for (int r = 0; r < 4; ++r) {
        float f = (float)c1[n][r] * fsc1 + ((const float*)&bb)[r];
        float gg = gelu_f(f);
        g[n][r] = gg;
        sum2 = fmaf(gg, gg, sum2);
        am2 = fmaxf(am2, fabsf(gg));
      }
    }
    sum2 += __shfl_xor(sum2, 16, 64);
    sum2 += __shfl_xor(sum2, 32, 64);
    am2 = fmaxf(am2, __shfl_xor(am2, 16, 64));
    am2 = fmaxf(am2, __shfl_xor(am2, 32, 64));

    const float n2v = sqrtf(sum2);
    const float inv2 = rcp_nr(fmaxf(n2v, 1e-12f));
    const float axc2 = fmaxf(am2 * 16.f * inv2, 1e-5f);
    const float sx2 = 127.f * rcp_nr(axc2);
    const float qs2 = 16.f * inv2 * sx2;
    const float fsc2 = m2c * axc2 * (1.f / 127.f);

    #pragma unroll
    for (int n = 0; n < 16; ++n) {
      int q0 = (int)fminf(fmaxf(rintf(g[n][0] * qs2), -128.f), 127.f);
      int q1i = (int)fminf(fmaxf(rintf(g[n][1] * qs2), -128.f), 127.f);
      int q2 = (int)fminf(fmaxf(rintf(g[n][2] * qs2), -128.f), 127.f);
      int q3 = (int)fminf(fmaxf(rintf(g[n][3] * qs2), -128.f), 127.f);
      unsigned pk = (unsigned)(q0 & 255) | ((unsigned)(q1i & 255) << 8) |
                    ((unsigned)(q2 & 255) << 16) | ((unsigned)(q3 & 255) << 24);
      qf2w[col * 66 + n * 4 + hi] = pk;
    }

    // BitLinear2 (MFMA), K=256 in 8 k-steps; B rebuilt from unsigned loads
    i32x4 c2[4];
    #pragma unroll
    for (int n2 = 0; n2 < 4; ++n2) c2[n2] = (i32x4){0, 0, 0, 0};
    #pragma unroll
    for (int ks = 0; ks < 8; ++ks) {
      const unsigned* brow = &qf2w[col * 66 + ks * 8 + hi * 2];
      const long long bfr = mk64(brow[0], brow[1]);
      #pragma unroll
      for (int n2 = 0; n2 < 4; ++n2) {
        const long long afr =
            *(const long long*)&w2p[(n2 * 16 + col) * 264 + ks * 32 + hi * 8];
        c2[n2] = __builtin_amdgcn_mfma_i32_16x16x32_i8(afr, bfr, c2[n2], 0, 0, 0);
      }
    }

    // epilogue: dequant + b2 + residual (h already in regs), store
    #pragma unroll
    for (int n2 = 0; n2 < 4; ++n2) {
      const float4 bb = *(const float4*)&b2s[n2 * 16 + hi * 4];
      #pragma unroll
      for (int r = 0; r < 4; ++r) {
        float v = (float)c2[n2][r] * fsc2 + ((const float*)&bb)[r] +
                  hacc[tl][n2][r];
        dout[gbase + (((size_t)(n2 * 16 + 4 * hi + r)) << 14) + rowoff + t0 +
             col] = v;
      }
    }
  }
}

extern "C" void kernel_launch(void* const* d_in, const int* in_sizes, int n_in,
                              void* d_out, int out_size, void* d_ws, size_t ws_size,
                              hipStream_t stream) {
  (void)in_sizes; (void)n_in; (void)out_size; (void)ws_size;
  const float* x   = (const float*)d_in[0];
  const float* dww = (const float*)d_in[1];
  const float* dwb = (const float*)d_in[2];
  const float* pww = (const float*)d_in[3];
  const float* pwb = (const float*)d_in[4];
  const float* lnw = (const float*)d_in[5];
  const float* lnb = (const float*)d_in[6];
  const float* w1  = (const float*)d_in[7];
  const float* b1  = (const float*)d_in[8];
  const float* w2  = (const float*)d_in[9];
  const float* b2  = (const float*)d_in[10];
  float* out = (float*)d_out;

  float* scales = (float*)d_ws;
  unsigned* u1p = (unsigned*)((char*)d_ws + 16);
  unsigned* u2p = u1p + 4096;

  hipLaunchKernelGGL(k_prep, dim3(2), dim3(256), 0, stream, w1, w2, scales, u1p, u2p);
  hipLaunchKernelGGL(k_dw, dim3(64, 64, 16), dim3(256), 0, stream,
                     x, dww, dwb, out);
  hipLaunchKernelGGL(k_fused, dim3(128, 16), dim3(256), 0, stream,
                     pww, pwb, lnw, lnb, b1, b2, scales, u1p, u2p, out);
}

// Round 5
// 317.662 us; speedup vs baseline: 1.6758x; 1.0201x over previous
//
#include <hip/hip_runtime.h>

#define DEVINL __device__ __forceinline__

typedef __attribute__((ext_vector_type(4))) int i32x4;
typedef __attribute__((ext_vector_type(4))) float f32x4;
typedef __attribute__((ext_vector_type(8))) __bf16 bf16x8;

DEVINL float rcp_nr(float x) {
  float r = __builtin_amdgcn_rcpf(x);
  return r * (2.0f - x * r);
}
DEVINL float rsq_nr(float x) {
  float r = __builtin_amdgcn_rsqf(x);
  return r * (1.5f - 0.5f * x * r * r);
}
// exact-GELU via Abramowitz-Stegun 7.1.26 erf (|abs err| < 1.5e-7), branchless
DEVINL float gelu_f(float x) {
  float z = fabsf(x) * 0.7071067811865476f;
  float t = rcp_nr(fmaf(0.3275911f, z, 1.0f));
  float p = fmaf(1.061405429f, t, -1.453152027f);
  p = fmaf(p, t, 1.421413741f);
  p = fmaf(p, t, -0.284496736f);
  p = fmaf(p, t, 0.254829592f);
  p = p * t;
  float er = fmaf(-p, __expf(-z * z), 1.0f);
  er = copysignf(er, x);
  return 0.5f * x * (1.0f + er);
}

DEVINL unsigned packq4(float a, float b, float c, float d, float scale) {
  int ia = (int)fminf(fmaxf(rintf(a * scale), -1.f), 1.f);
  int ib = (int)fminf(fmaxf(rintf(b * scale), -1.f), 1.f);
  int ic = (int)fminf(fmaxf(rintf(c * scale), -1.f), 1.f);
  int id = (int)fminf(fmaxf(rintf(d * scale), -1.f), 1.f);
  return (unsigned)(ia & 255) | ((unsigned)(ib & 255) << 8) |
         ((unsigned)(ic & 255) << 16) | ((unsigned)(id & 255) << 24);
}

DEVINL long long mk64(unsigned lo, unsigned hi) {
  return (long long)(((unsigned long long)hi << 32) | (unsigned long long)lo);
}

// ------ kernel 0: ternary pack (blocks 0,1) + pw bf16 hi/lo split (block 2) --
__global__ __launch_bounds__(256) void k_prep(
    const float* __restrict__ w1, const float* __restrict__ w2,
    const float* __restrict__ pww, float* __restrict__ scales,
    unsigned* __restrict__ u1p, unsigned* __restrict__ u2p,
    unsigned short* __restrict__ pwbf) {
  const int tid = threadIdx.x;
  const int bx = blockIdx.x;

  if (bx == 2) {
    // MFMA A-fragment layout: entry e = ((n2*2+kh)*64 + lane)*8 + j holds
    // pw[(n2*16 + (lane&15))][kh*32 + (lane>>4)*8 + j], split hi/lo bf16.
    for (int e = tid; e < 4096; e += 256) {
      int n2 = e >> 10, kh = (e >> 9) & 1, ln = (e >> 3) & 63, j = e & 7;
      int c = ln & 15, hh = ln >> 4;
      float v = pww[(n2 * 16 + c) * 64 + kh * 32 + hh * 8 + j];
      __bf16 hb = (__bf16)v;
      __bf16 lb = (__bf16)(v - (float)hb);
      pwbf[e] = __builtin_bit_cast(unsigned short, hb);
      pwbf[e + 4096] = __builtin_bit_cast(unsigned short, lb);
    }
    return;
  }

  __shared__ double red[4];
  __shared__ float mclip_s;
  const float* w = (bx == 0) ? w1 : w2;

  double s = 0.0;
  for (int e = tid; e < 16384; e += 256) s += (double)fabsf(w[e]);
  #pragma unroll
  for (int m = 32; m; m >>= 1) s += __shfl_xor(s, m, 64);
  if ((tid & 63) == 0) red[tid >> 6] = s;
  __syncthreads();
  if (tid == 0) {
    double tot = red[0] + red[1] + red[2] + red[3];
    float mc = fmaxf((float)(tot / 16384.0), 1e-5f);
    scales[bx] = mc;
    mclip_s = mc;
  }
  __syncthreads();
  const float scale = 1.0f / mclip_s;

  if (bx == 0) {
    for (int e = tid; e < 4096; e += 256) {
      float4 v = *(const float4*)(w1 + e * 4);
      u1p[e] = packq4(v.x, v.y, v.z, v.w, scale);
    }
  } else {
    for (int e = tid; e < 4096; e += 256) {
      float4 v = *(const float4*)(w2 + e * 4);
      u2p[e] = packq4(v.x, v.y, v.z, v.w, scale);
    }
  }
}

// ---------------- kernel 1: depthwise 3x3 stencil (streaming) ----------------
__global__ __launch_bounds__(256) void k_dw(
    const float* __restrict__ x, const float* __restrict__ dww,
    const float* __restrict__ dwb, float* __restrict__ dout) {
  const int tid = threadIdx.x;
  const int px = tid & 127, ry = tid >> 7;
  const int y = blockIdx.x * 2 + ry;
  const int c = blockIdx.y;
  const int bz = blockIdx.z;
  const float* xc = x + (((size_t)bz * 64 + c) << 14);

  float wv[9];
  #pragma unroll
  for (int i = 0; i < 9; ++i) wv[i] = dww[c * 9 + i];
  float acc = dwb[c];
  #pragma unroll
  for (int dy = 0; dy < 3; ++dy) {
    int iy = y + dy - 1;
    if ((unsigned)iy < 128u) {
      const float* row = xc + (iy << 7);
      #pragma unroll
      for (int dx = 0; dx < 3; ++dx) {
        int ix = px + dx - 1;
        if ((unsigned)ix < 128u) acc = fmaf(row[ix], wv[dy * 3 + dx], acc);
      }
    }
  }
  dout[(((size_t)bz * 64 + c) << 14) + (y << 7) + px] = acc;
}

// ------ kernel 2: pw 1x1 (bf16x3 MFMA) + LN + BitFF(i8 MFMA) + residual -----
// Block = 256 threads (4 waves) = one row y of one image (128 tokens).
// Thread (col=lane&15, hi=lane>>4) of wave w owns token 32w+16tl+col and
// channels {16n2+4hi+r} — the MFMA 16x16 C/D layout for ALL three GEMMs.
// Phase P: h(dw out) loaded straight from global into B-frags (read once),
//   pw via 3-term bf16 split MFMA, hacc in regs.
// Tile loop: N (LN+rms1+quant, 2 shfl) -> BL1 i8 MFMA -> GELU -> rms2+quant
//   -> BL2 i8 MFMA -> +h residual -> store.
// LDS: uni region holds pw A-frags in phase P, per-wave wq/qf2 in phase M
// (barrier-separated, r3-proven same-type unsigned discipline inside phases).
__global__ __launch_bounds__(256, 2) void k_fused(
    const float* __restrict__ pwb, const float* __restrict__ lnw,
    const float* __restrict__ lnb, const float* __restrict__ b1,
    const float* __restrict__ b2, const float* __restrict__ scales,
    const unsigned* __restrict__ u1p, const unsigned* __restrict__ u2p,
    const uint4* __restrict__ pwbf, float* __restrict__ dout) {
  __shared__ __align__(16) char uni[4][6272];          // P: pwbf(16K) M: wq/qf2
  __shared__ __align__(16) signed char w2p[64 * 264];  // [o][k] pad 264
  __shared__ float pwb_s[64], lnw_s[64], lnb_s[64], b2s[64];
  __shared__ float b1s[256];
  __shared__ float sc_s[2];

  const int tid = threadIdx.x;
  const int w = tid >> 6, lane = tid & 63;
  const int col = lane & 15, hi = lane >> 4;
  const int y = blockIdx.x, bz = blockIdx.y;
  const size_t gbase = ((size_t)bz * 64) << 14;
  const int rowoff = y * 128;
  const int tcol = rowoff + w * 32 + col;

  // ---- issue h loads upfront (32 independent scalar loads, 64B segments) ---
  float hv[2][2][8];
  #pragma unroll
  for (int tl = 0; tl < 2; ++tl)
    #pragma unroll
    for (int kh = 0; kh < 2; ++kh)
      #pragma unroll
      for (int j = 0; j < 8; ++j) {
        int cg = kh * 32 + hi * 8 + j;
        hv[tl][kh][j] = dout[gbase + ((size_t)cg << 14) + tcol + tl * 16];
      }

  // ---- stage weights ----
  {
    uint4* pwl = (uint4*)&uni[0][0];
    for (int e = tid; e < 1024; e += 256) pwl[e] = pwbf[e];  // 16 KB hi+lo
  }
  for (int e = tid; e < 4096; e += 256) {
    int o = e >> 6, d = e & 63;
    ((unsigned*)w2p)[o * 66 + d] = u2p[e];
  }
  if (tid < 64) {
    pwb_s[tid] = pwb[tid]; lnw_s[tid] = lnw[tid];
    lnb_s[tid] = lnb[tid]; b2s[tid] = b2[tid];
  }
  b1s[tid] = b1[tid];
  if (tid < 2) sc_s[tid] = scales[tid];

  // w1 ternary A-fragments -> registers
  long long w1a0[16], w1a1[16];
  #pragma unroll
  for (int n = 0; n < 16; ++n) {
    const unsigned* q = &u1p[(n * 16 + col) * 16];
    uint2 lo = *(const uint2*)&q[2 * hi];
    uint2 hh = *(const uint2*)&q[8 + 2 * hi];
    w1a0[n] = mk64(lo.x, lo.y);
    w1a1[n] = mk64(hh.x, hh.y);
  }
  __syncthreads();  // weights + pw frags visible

  // ---- Phase P: pointwise GEMM on MFMA (bf16 hi/lo 3-term split) ----
  const uint4* pwfrag = (const uint4*)&uni[0][0];
  float hacc[2][4][4];
  #pragma unroll
  for (int tl = 0; tl < 2; ++tl) {
    bf16x8 bh[2], bl[2];
    #pragma unroll
    for (int kh = 0; kh < 2; ++kh)
      #pragma unroll
      for (int j = 0; j < 8; ++j) {
        float v = hv[tl][kh][j];
        __bf16 hb = (__bf16)v;
        bh[kh][j] = hb;
        bl[kh][j] = (__bf16)(v - (float)hb);
      }
    #pragma unroll
    for (int n2 = 0; n2 < 4; ++n2) {
      f32x4 acc = {0.f, 0.f, 0.f, 0.f};
      #pragma unroll
      for (int kh = 0; kh < 2; ++kh) {
        uint4 ahw = pwfrag[(n2 * 2 + kh) * 64 + lane];
        uint4 alw = pwfrag[(n2 * 2 + kh) * 64 + lane + 512];
        bf16x8 ah = __builtin_bit_cast(bf16x8, ahw);
        bf16x8 al = __builtin_bit_cast(bf16x8, alw);
        acc = __builtin_amdgcn_mfma_f32_16x16x32_bf16(ah, bh[kh], acc, 0, 0, 0);
        acc = __builtin_amdgcn_mfma_f32_16x16x32_bf16(ah, bl[kh], acc, 0, 0, 0);
        acc = __builtin_amdgcn_mfma_f32_16x16x32_bf16(al, bh[kh], acc, 0, 0, 0);
      }
      #pragma unroll
      for (int r = 0; r < 4; ++r)
        hacc[tl][n2][r] = acc[r] + pwb_s[n2 * 16 + 4 * hi + r];
    }
  }
  __syncthreads();  // pw frags dead -> uni becomes per-wave wq/qf2 (TBAA fence)

  unsigned* wq = (unsigned*)&uni[w][0];      // [2 tl][16 tok][16 dw]
  unsigned* qf2w = (unsigned*)&uni[w][2048]; // [16 tok][66 dw]
  const float sc0 = sc_s[0], m2c = sc_s[1];

  for (int tl = 0; tl < 2; ++tl) {
    const int t0 = w * 32 + tl * 16;

    // ---- Phase N: LayerNorm + rms1 + int8 quant (shfl over hi-group) ----
    float s1 = 0.f, q1 = 0.f;
    #pragma unroll
    for (int n2 = 0; n2 < 4; ++n2)
      #pragma unroll
      for (int r = 0; r < 4; ++r) {
        float v = hacc[tl][n2][r];
        s1 += v;
        q1 = fmaf(v, v, q1);
      }
    s1 += __shfl_xor(s1, 16, 64); s1 += __shfl_xor(s1, 32, 64);
    q1 += __shfl_xor(q1, 16, 64); q1 += __shfl_xor(q1, 32, 64);
    const float mu = s1 * (1.f / 64.f);
    const float var = fmaxf(q1 * (1.f / 64.f) - mu * mu, 0.f);
    const float istd = rsq_nr(var + 1e-5f);

    float tn[4][4];
    float s2 = 0.f, am = 0.f;
    #pragma unroll
    for (int n2 = 0; n2 < 4; ++n2) {
      float4 lw = *(const float4*)&lnw_s[n2 * 16 + 4 * hi];
      float4 lb = *(const float4*)&lnb_s[n2 * 16 + 4 * hi];
      #pragma unroll
      for (int r = 0; r < 4; ++r) {
        float t = (hacc[tl][n2][r] - mu) * istd * ((const float*)&lw)[r] +
                  ((const float*)&lb)[r];
        tn[n2][r] = t;
        s2 = fmaf(t, t, s2);
        am = fmaxf(am, fabsf(t));
      }
    }
    s2 += __shfl_xor(s2, 16, 64); s2 += __shfl_xor(s2, 32, 64);
    am = fmaxf(am, __shfl_xor(am, 16, 64));
    am = fmaxf(am, __shfl_xor(am, 32, 64));

    const float n1 = sqrtf(s2);
    const float inv1 = rcp_nr(fmaxf(n1, 1e-12f));
    const float axc1 = fmaxf(am * 8.f * inv1, 1e-5f);
    const float sx1 = 127.f * rcp_nr(axc1);
    const float qs1 = 8.f * inv1 * sx1;
    const float fsc1 = sc0 * axc1 * (1.f / 127.f);

    #pragma unroll
    for (int n2 = 0; n2 < 4; ++n2) {
      int v0 = (int)fminf(fmaxf(rintf(tn[n2][0] * qs1), -128.f), 127.f);
      int v1 = (int)fminf(fmaxf(rintf(tn[n2][1] * qs1), -128.f), 127.f);
      int v2 = (int)fminf(fmaxf(rintf(tn[n2][2] * qs1), -128.f), 127.f);
      int v3 = (int)fminf(fmaxf(rintf(tn[n2][3] * qs1), -128.f), 127.f);
      unsigned pk = (unsigned)(v0 & 255) | ((unsigned)(v1 & 255) << 8) |
                    ((unsigned)(v2 & 255) << 16) | ((unsigned)(v3 & 255) << 24);
      wq[tl * 256 + col * 16 + n2 * 4 + hi] = pk;
    }

    // ---- BitLinear1 (i8 MFMA) ----
    const unsigned* wqt = &wq[tl * 256 + col * 16];
    const long long bq0 = mk64(wqt[2 * hi], wqt[2 * hi + 1]);
    const long long bq1 = mk64(wqt[8 + 2 * hi], wqt[8 + 2 * hi + 1]);

    i32x4 c1[16];
    #pragma unroll
    for (int n = 0; n < 16; ++n) {
      i32x4 cc = {0, 0, 0, 0};
      cc = __builtin_amdgcn_mfma_i32_16x16x32_i8(w1a0[n], bq0, cc, 0, 0, 0);
      cc = __builtin_amdgcn_mfma_i32_16x16x32_i8(w1a1[n], bq1, cc, 0, 0, 0);
      c1[n] = cc;
    }

    // dequant + bias + exact GELU; rms2/amax partials
    float g[16][4];
    float sum2 = 0.f, am2 = 0.f;
    #pragma unroll
    for (int n = 0; n < 16; ++n) {
      const float4 bb = *(const float4*)&b1s[n * 16 + hi * 4];
      #pragma unroll
      for (int r = 0; r < 4; ++r) {
        float f = (float)c1[n][r] * fsc1 + ((const float*)&bb)[r];
        float gg = gelu_f(f);
        g[n][r] = gg;
        sum2 = fmaf(gg, gg, sum2);
        am2 = fmaxf(am2, fabsf(gg));
      }
    }
    sum2 += __shfl_xor(sum2, 16, 64);
    sum2 += __shfl_xor(sum2, 32, 64);
    am2 = fmaxf(am2, __shfl_xor(am2, 16, 64));
    am2 = fmaxf(am2, __shfl_xor(am2, 32, 64));

    const float n2v = sqrtf(sum2);
    const float inv2 = rcp_nr(fmaxf(n2v, 1e-12f));
    const float axc2 = fmaxf(am2 * 16.f * inv2, 1e-5f);
    const float sx2 = 127.f * rcp_nr(axc2);
    const float qs2 = 16.f * inv2 * sx2;
    const float fsc2 = m2c * axc2 * (1.f / 127.f);

    #pragma unroll
    for (int n = 0; n < 16; ++n) {
      int q0 = (int)fminf(fmaxf(rintf(g[n][0] * qs2), -128.f), 127.f);
      int q1i = (int)fminf(fmaxf(rintf(g[n][1] * qs2), -128.f), 127.f);
      int q2 = (int)fminf(fmaxf(rintf(g[n][2] * qs2), -128.f), 127.f);
      int q3 = (int)fminf(fmaxf(rintf(g[n][3] * qs2), -128.f), 127.f);
      unsigned pk = (unsigned)(q0 & 255) | ((unsigned)(q1i & 255) << 8) |
                    ((unsigned)(q2 & 255) << 16) | ((unsigned)(q3 & 255) << 24);
      qf2w[col * 66 + n * 4 + hi] = pk;
    }

    // ---- BitLinear2 (i8 MFMA), K=256 in 8 k-steps ----
    i32x4 c2[4];
    #pragma unroll
    for (int n2 = 0; n2 < 4; ++n2) c2[n2] = (i32x4){0, 0, 0, 0};
    #pragma unroll
    for (int ks = 0; ks < 8; ++ks) {
      const unsigned* brow = &qf2w[col * 66 + ks * 8 + hi * 2];
      const long long bfr = mk64(brow[0], brow[1]);
      #pragma unroll
      for (int n2 = 0; n2 < 4; ++n2) {
        const long long afr =
            *(const long long*)&w2p[(n2 * 16 + col) * 264 + ks * 32 + hi * 8];
        c2[n2] = __builtin_amdgcn_mfma_i32_16x16x32_i8(afr, bfr, c2[n2], 0, 0, 0);
      }
    }

    // ---- epilogue: dequant + b2 + residual (h in regs), store ----
    #pragma unroll
    for (int n2 = 0; n2 < 4; ++n2) {
      const float4 bb = *(const float4*)&b2s[n2 * 16 + hi * 4];
      #pragma unroll
      for (int r = 0; r < 4; ++r) {
        float v = (float)c2[n2][r] * fsc2 + ((const float*)&bb)[r] +
                  hacc[tl][n2][r];
        dout[gbase + (((size_t)(n2 * 16 + 4 * hi + r)) << 14) + rowoff + t0 +
             col] = v;
      }
    }
  }
}

extern "C" void kernel_launch(void* const* d_in, const int* in_sizes, int n_in,
                              void* d_out, int out_size, void* d_ws, size_t ws_size,
                              hipStream_t stream) {
  (void)in_sizes; (void)n_in; (void)out_size; (void)ws_size;
  const float* x   = (const float*)d_in[0];
  const float* dww = (const float*)d_in[1];
  const float* dwb = (const float*)d_in[2];
  const float* pww = (const float*)d_in[3];
  const float* pwb = (const float*)d_in[4];
  const float* lnw = (const float*)d_in[5];
  const float* lnb = (const float*)d_in[6];
  const float* w1  = (const float*)d_in[7];
  const float* b1  = (const float*)d_in[8];
  const float* w2  = (const float*)d_in[9];
  const float* b2  = (const float*)d_in[10];
  float* out = (float*)d_out;

  float* scales = (float*)d_ws;
  unsigned* u1p = (unsigned*)((char*)d_ws + 16);
  unsigned* u2p = u1p + 4096;
  unsigned short* pwbf = (unsigned short*)((char*)d_ws + 16 + 32768);

  hipLaunchKernelGGL(k_prep, dim3(3), dim3(256), 0, stream,
                     w1, w2, pww, scales, u1p, u2p, pwbf);
  hipLaunchKernelGGL(k_dw, dim3(64, 64, 16), dim3(256), 0, stream,
                     x, dww, dwb, out);
  hipLaunchKernelGGL(k_fused, dim3(128, 16), dim3(256), 0, stream,
                     pwb, lnw, lnb, b1, b2, scales, u1p, u2p,
                     (const uint4*)pwbf, out);
}

// Round 6
// 227.959 us; speedup vs baseline: 2.3353x; 1.3935x over previous
//
#include <hip/hip_runtime.h>

#define DEVINL __device__ __forceinline__

typedef __attribute__((ext_vector_type(4))) int i32x4;
typedef __attribute__((ext_vector_type(4))) float f32x4;
typedef __attribute__((ext_vector_type(8))) __bf16 bf16x8;

DEVINL float rcp_nr(float x) {
  float r = __builtin_amdgcn_rcpf(x);
  return r * (2.0f - x * r);
}
DEVINL float rsq_nr(float x) {
  float r = __builtin_amdgcn_rsqf(x);
  return r * (1.5f - 0.5f * x * r * r);
}
// exact-GELU via Abramowitz-Stegun 7.1.26 erf (|abs err| < 1.5e-7), branchless
DEVINL float gelu_f(float x) {
  float z = fabsf(x) * 0.7071067811865476f;
  float t = rcp_nr(fmaf(0.3275911f, z, 1.0f));
  float p = fmaf(1.061405429f, t, -1.453152027f);
  p = fmaf(p, t, 1.421413741f);
  p = fmaf(p, t, -0.284496736f);
  p = fmaf(p, t, 0.254829592f);
  p = p * t;
  float er = fmaf(-p, __expf(-z * z), 1.0f);
  er = copysignf(er, x);
  return 0.5f * x * (1.0f + er);
}

DEVINL unsigned packq4(float a, float b, float c, float d, float scale) {
  int ia = (int)fminf(fmaxf(rintf(a * scale), -1.f), 1.f);
  int ib = (int)fminf(fmaxf(rintf(b * scale), -1.f), 1.f);
  int ic = (int)fminf(fmaxf(rintf(c * scale), -1.f), 1.f);
  int id = (int)fminf(fmaxf(rintf(d * scale), -1.f), 1.f);
  return (unsigned)(ia & 255) | ((unsigned)(ib & 255) << 8) |
         ((unsigned)(ic & 255) << 16) | ((unsigned)(id & 255) << 24);
}

DEVINL long long mk64(unsigned lo, unsigned hi) {
  return (long long)(((unsigned long long)hi << 32) | (unsigned long long)lo);
}

// ------ kernel 0: ternary pack in MFMA-FRAG ORDER + pw bf16 hi/lo split -----
// u1f dword e: n=e>>8, lane=(e>>2)&63, word=e&3; frag uint4 of (n,lane) =
//   {a0.lo,a0.hi,a1.lo,a1.hi}; kdw = (word>>1)*8 + (lane>>4)*2 + (word&1);
//   row r = n*16 + (lane&15); source = w1[r*64 + kdw*4 .. +3].
// u2f dword e: ks=e>>9, n2=(e>>7)&3, lane=(e>>1)&63, word=e&1;
//   kdw = ks*8 + (lane>>4)*2 + word; r = n2*16 + (lane&15);
//   source = w2[r*256 + kdw*4 .. +3].
__global__ __launch_bounds__(256) void k_prep(
    const float* __restrict__ w1, const float* __restrict__ w2,
    const float* __restrict__ pww, float* __restrict__ scales,
    unsigned* __restrict__ u1f, unsigned* __restrict__ u2f,
    unsigned short* __restrict__ pwbf) {
  const int tid = threadIdx.x;
  const int bx = blockIdx.x;

  if (bx == 2) {
    // pw A-frag: entry e = ((n2*2+kh)*64 + lane)*8 + j holds
    // pw[(n2*16 + (lane&15))][kh*32 + (lane>>4)*8 + j], split hi/lo bf16.
    for (int e = tid; e < 4096; e += 256) {
      int n2 = e >> 10, kh = (e >> 9) & 1, ln = (e >> 3) & 63, j = e & 7;
      int c = ln & 15, hh = ln >> 4;
      float v = pww[(n2 * 16 + c) * 64 + kh * 32 + hh * 8 + j];
      __bf16 hb = (__bf16)v;
      __bf16 lb = (__bf16)(v - (float)hb);
      pwbf[e] = __builtin_bit_cast(unsigned short, hb);
      pwbf[e + 4096] = __builtin_bit_cast(unsigned short, lb);
    }
    return;
  }

  __shared__ double red[4];
  __shared__ float mclip_s;
  const float* w = (bx == 0) ? w1 : w2;

  double s = 0.0;
  for (int e = tid; e < 16384; e += 256) s += (double)fabsf(w[e]);
  #pragma unroll
  for (int m = 32; m; m >>= 1) s += __shfl_xor(s, m, 64);
  if ((tid & 63) == 0) red[tid >> 6] = s;
  __syncthreads();
  if (tid == 0) {
    double tot = red[0] + red[1] + red[2] + red[3];
    float mc = fmaxf((float)(tot / 16384.0), 1e-5f);
    scales[bx] = mc;
    mclip_s = mc;
  }
  __syncthreads();
  const float scale = 1.0f / mclip_s;

  if (bx == 0) {
    for (int e = tid; e < 4096; e += 256) {
      int n = e >> 8, lane = (e >> 2) & 63, word = e & 3;
      int r = n * 16 + (lane & 15);
      int kdw = (word >> 1) * 8 + (lane >> 4) * 2 + (word & 1);
      const float* src = w1 + (r * 16 + kdw) * 4;
      u1f[e] = packq4(src[0], src[1], src[2], src[3], scale);
    }
  } else {
    for (int e = tid; e < 4096; e += 256) {
      int ks = e >> 9, n2 = (e >> 7) & 3, lane = (e >> 1) & 63, word = e & 1;
      int r = n2 * 16 + (lane & 15);
      int kdw = ks * 8 + (lane >> 4) * 2 + word;
      const float* src = w2 + (r * 64 + kdw) * 4;
      u2f[e] = packq4(src[0], src[1], src[2], src[3], scale);
    }
  }
}

// ---------------- kernel 1: depthwise 3x3 stencil (unchanged) ----------------
__global__ __launch_bounds__(256) void k_dw(
    const float* __restrict__ x, const float* __restrict__ dww,
    const float* __restrict__ dwb, float* __restrict__ dout) {
  const int tid = threadIdx.x;
  const int px = tid & 127, ry = tid >> 7;
  const int y = blockIdx.x * 2 + ry;
  const int c = blockIdx.y;
  const int bz = blockIdx.z;
  const float* xc = x + (((size_t)bz * 64 + c) << 14);

  float wv[9];
  #pragma unroll
  for (int i = 0; i < 9; ++i) wv[i] = dww[c * 9 + i];
  float acc = dwb[c];
  #pragma unroll
  for (int dy = 0; dy < 3; ++dy) {
    int iy = y + dy - 1;
    if ((unsigned)iy < 128u) {
      const float* row = xc + (iy << 7);
      #pragma unroll
      for (int dx = 0; dx < 3; ++dx) {
        int ix = px + dx - 1;
        if ((unsigned)ix < 128u) acc = fmaf(row[ix], wv[dy * 3 + dx], acc);
      }
    }
  }
  dout[(((size_t)bz * 64 + c) << 14) + (y << 7) + px] = acc;
}

// ------ kernel 2: pw (bf16x3 MFMA) + LN + BitFF(i8 MFMA) + residual ---------
// Spill-free restructure of r5: w1/w2 A-frags come from LDS per MFMA
// (frag-ordered, lane-contiguous ds_read), BL1->GELU interleaved per n
// (c1 transient), pw A-frags straight from global (L2-hot).
// Peak live ~ g[64] + hacc[32] + misc ~ 150 regs.
__global__ __launch_bounds__(256, 2) void k_fused(
    const float* __restrict__ pwb, const float* __restrict__ lnw,
    const float* __restrict__ lnb, const float* __restrict__ b1,
    const float* __restrict__ b2, const float* __restrict__ scales,
    const unsigned* __restrict__ u1f, const unsigned* __restrict__ u2f,
    const uint4* __restrict__ pwf, float* __restrict__ dout) {
  __shared__ __align__(16) unsigned w1f[4096];     // [n][lane] uint4 frags
  __shared__ __align__(16) unsigned w2f[4096];     // [ks][n2][lane] qwords
  __shared__ __align__(16) unsigned ubuf[4][1088]; // per-wave wq/qf2 union
  __shared__ float b1s[256];
  __shared__ float pwb_s[64], lnw_s[64], lnb_s[64], b2s[64];
  __shared__ float sc_s[2];

  const int tid = threadIdx.x;
  const int w = tid >> 6, lane = tid & 63;
  const int col = lane & 15, hi = lane >> 4;
  const int y = blockIdx.x, bz = blockIdx.y;
  const size_t gbase = ((size_t)bz * 64) << 14;
  const int tokbase = y * 128 + w * 32 + col;

  // ---- issue h (dw output) loads upfront ----
  float hv[2][2][8];
  #pragma unroll
  for (int tl = 0; tl < 2; ++tl)
    #pragma unroll
    for (int kh = 0; kh < 2; ++kh)
      #pragma unroll
      for (int j = 0; j < 8; ++j)
        hv[tl][kh][j] =
            dout[gbase + (((size_t)(kh * 32 + hi * 8 + j)) << 14) + tokbase +
                 tl * 16];

  // ---- pw A-frags from global (16 KB, L2-hot) ----
  uint4 pwa[4][2], pwl[4][2];
  #pragma unroll
  for (int n2 = 0; n2 < 4; ++n2)
    #pragma unroll
    for (int kh = 0; kh < 2; ++kh) {
      pwa[n2][kh] = pwf[(n2 * 2 + kh) * 64 + lane];
      pwl[n2][kh] = pwf[(n2 * 2 + kh) * 64 + lane + 512];
    }

  // ---- stage LDS ----
  for (int e = tid; e < 4096; e += 256) w1f[e] = u1f[e];
  for (int e = tid; e < 4096; e += 256) w2f[e] = u2f[e];
  if (tid < 64) {
    pwb_s[tid] = pwb[tid]; lnw_s[tid] = lnw[tid];
    lnb_s[tid] = lnb[tid]; b2s[tid] = b2[tid];
  }
  b1s[tid] = b1[tid];
  if (tid < 2) sc_s[tid] = scales[tid];
  __syncthreads();

  const float sc0 = sc_s[0], m2c = sc_s[1];

  // ---- pointwise GEMM on MFMA (bf16 hi/lo 3-term split), both tiles ----
  float hacc[2][4][4];
  #pragma unroll
  for (int tl = 0; tl < 2; ++tl) {
    bf16x8 bh[2], bl[2];
    #pragma unroll
    for (int kh = 0; kh < 2; ++kh)
      #pragma unroll
      for (int j = 0; j < 8; ++j) {
        float v = hv[tl][kh][j];
        __bf16 hb = (__bf16)v;
        bh[kh][j] = hb;
        bl[kh][j] = (__bf16)(v - (float)hb);
      }
    #pragma unroll
    for (int n2 = 0; n2 < 4; ++n2) {
      f32x4 acc = {0.f, 0.f, 0.f, 0.f};
      #pragma unroll
      for (int kh = 0; kh < 2; ++kh) {
        bf16x8 ah = __builtin_bit_cast(bf16x8, pwa[n2][kh]);
        bf16x8 al = __builtin_bit_cast(bf16x8, pwl[n2][kh]);
        acc = __builtin_amdgcn_mfma_f32_16x16x32_bf16(ah, bh[kh], acc, 0, 0, 0);
        acc = __builtin_amdgcn_mfma_f32_16x16x32_bf16(ah, bl[kh], acc, 0, 0, 0);
        acc = __builtin_amdgcn_mfma_f32_16x16x32_bf16(al, bh[kh], acc, 0, 0, 0);
      }
      #pragma unroll
      for (int r = 0; r < 4; ++r)
        hacc[tl][n2][r] = acc[r] + pwb_s[n2 * 16 + 4 * hi + r];
    }
  }

  unsigned* buf = ubuf[w];  // wave-local; wq then qf2 (overlap is program-order safe)

  #pragma unroll
  for (int tl = 0; tl < 2; ++tl) {
    // ---- LayerNorm + rms1 + int8 quant ----
    float s1 = 0.f, q1 = 0.f;
    #pragma unroll
    for (int n2 = 0; n2 < 4; ++n2)
      #pragma unroll
      for (int r = 0; r < 4; ++r) {
        float v = hacc[tl][n2][r];
        s1 += v;
        q1 = fmaf(v, v, q1);
      }
    s1 += __shfl_xor(s1, 16, 64); s1 += __shfl_xor(s1, 32, 64);
    q1 += __shfl_xor(q1, 16, 64); q1 += __shfl_xor(q1, 32, 64);
    const float mu = s1 * (1.f / 64.f);
    const float var = fmaxf(q1 * (1.f / 64.f) - mu * mu, 0.f);
    const float istd = rsq_nr(var + 1e-5f);

    float tn[4][4];
    float s2 = 0.f, am = 0.f;
    #pragma unroll
    for (int n2 = 0; n2 < 4; ++n2) {
      float4 lw = *(const float4*)&lnw_s[n2 * 16 + 4 * hi];
      float4 lb = *(const float4*)&lnb_s[n2 * 16 + 4 * hi];
      #pragma unroll
      for (int r = 0; r < 4; ++r) {
        float t = (hacc[tl][n2][r] - mu) * istd * ((const float*)&lw)[r] +
                  ((const float*)&lb)[r];
        tn[n2][r] = t;
        s2 = fmaf(t, t, s2);
        am = fmaxf(am, fabsf(t));
      }
    }
    s2 += __shfl_xor(s2, 16, 64); s2 += __shfl_xor(s2, 32, 64);
    am = fmaxf(am, __shfl_xor(am, 16, 64));
    am = fmaxf(am, __shfl_xor(am, 32, 64));

    const float n1 = sqrtf(s2);
    const float inv1 = rcp_nr(fmaxf(n1, 1e-12f));
    const float axc1 = fmaxf(am * 8.f * inv1, 1e-5f);
    const float sx1 = 127.f * rcp_nr(axc1);
    const float qs1 = 8.f * inv1 * sx1;
    const float fsc1 = sc0 * axc1 * (1.f / 127.f);

    #pragma unroll
    for (int n2 = 0; n2 < 4; ++n2) {
      int v0 = (int)fminf(fmaxf(rintf(tn[n2][0] * qs1), -128.f), 127.f);
      int v1 = (int)fminf(fmaxf(rintf(tn[n2][1] * qs1), -128.f), 127.f);
      int v2 = (int)fminf(fmaxf(rintf(tn[n2][2] * qs1), -128.f), 127.f);
      int v3 = (int)fminf(fmaxf(rintf(tn[n2][3] * qs1), -128.f), 127.f);
      unsigned pk = (unsigned)(v0 & 255) | ((unsigned)(v1 & 255) << 8) |
                    ((unsigned)(v2 & 255) << 16) | ((unsigned)(v3 & 255) << 24);
      buf[col * 16 + n2 * 4 + hi] = pk;
    }

    // B-frags for BL1 (read before any qf2 write can alias; wave program order)
    const long long bq0 = mk64(buf[col * 16 + 2 * hi], buf[col * 16 + 2 * hi + 1]);
    const long long bq1 =
        mk64(buf[col * 16 + 8 + 2 * hi], buf[col * 16 + 8 + 2 * hi + 1]);

    // ---- BitLinear1 (i8 MFMA) interleaved with dequant+GELU ----
    float g[16][4];
    float sum2 = 0.f, am2 = 0.f;
    #pragma unroll
    for (int n = 0; n < 16; ++n) {
      const uint4 wf = *(const uint4*)&w1f[(n * 64 + lane) * 4];
      i32x4 cc = {0, 0, 0, 0};
      cc = __builtin_amdgcn_mfma_i32_16x16x32_i8(mk64(wf.x, wf.y), bq0, cc, 0, 0, 0);
      cc = __builtin_amdgcn_mfma_i32_16x16x32_i8(mk64(wf.z, wf.w), bq1, cc, 0, 0, 0);
      const float4 bb = *(const float4*)&b1s[n * 16 + hi * 4];
      #pragma unroll
      for (int r = 0; r < 4; ++r) {
        float f = (float)cc[r] * fsc1 + ((const float*)&bb)[r];
        float gg = gelu_f(f);
        g[n][r] = gg;
        sum2 = fmaf(gg, gg, sum2);
        am2 = fmaxf(am2, fabsf(gg));
      }
    }
    sum2 += __shfl_xor(sum2, 16, 64);
    sum2 += __shfl_xor(sum2, 32, 64);
    am2 = fmaxf(am2, __shfl_xor(am2, 16, 64));
    am2 = fmaxf(am2, __shfl_xor(am2, 32, 64));

    const float n2v = sqrtf(sum2);
    const float inv2 = rcp_nr(fmaxf(n2v, 1e-12f));
    const float axc2 = fmaxf(am2 * 16.f * inv2, 1e-5f);
    const float sx2 = 127.f * rcp_nr(axc2);
    const float qs2 = 16.f * inv2 * sx2;
    const float fsc2 = m2c * axc2 * (1.f / 127.f);

    #pragma unroll
    for (int n = 0; n < 16; ++n) {
      int q0 = (int)fminf(fmaxf(rintf(g[n][0] * qs2), -128.f), 127.f);
      int q1i = (int)fminf(fmaxf(rintf(g[n][1] * qs2), -128.f), 127.f);
      int q2 = (int)fminf(fmaxf(rintf(g[n][2] * qs2), -128.f), 127.f);
      int q3 = (int)fminf(fmaxf(rintf(g[n][3] * qs2), -128.f), 127.f);
      unsigned pk = (unsigned)(q0 & 255) | ((unsigned)(q1i & 255) << 8) |
                    ((unsigned)(q2 & 255) << 16) | ((unsigned)(q3 & 255) << 24);
      buf[col * 66 + n * 4 + hi] = pk;
    }

    // ---- BitLinear2 (i8 MFMA), K=256 in 8 k-steps ----
    i32x4 c2[4];
    #pragma unroll
    for (int n2 = 0; n2 < 4; ++n2) c2[n2] = (i32x4){0, 0, 0, 0};
    #pragma unroll
    for (int ks = 0; ks < 8; ++ks) {
      const long long bfr =
          mk64(buf[col * 66 + ks * 8 + 2 * hi], buf[col * 66 + ks * 8 + 2 * hi + 1]);
      #pragma unroll
      for (int n2 = 0; n2 < 4; ++n2) {
        const unsigned* aw = &w2f[(((ks * 4 + n2) * 64) + lane) * 2];
        const long long afr = mk64(aw[0], aw[1]);
        c2[n2] = __builtin_amdgcn_mfma_i32_16x16x32_i8(afr, bfr, c2[n2], 0, 0, 0);
      }
    }

    // ---- epilogue: dequant + b2 + residual (hacc in regs), store ----
    #pragma unroll
    for (int n2 = 0; n2 < 4; ++n2) {
      const float4 bb = *(const float4*)&b2s[n2 * 16 + hi * 4];
      #pragma unroll
      for (int r = 0; r < 4; ++r) {
        float v = (float)c2[n2][r] * fsc2 + ((const float*)&bb)[r] +
                  hacc[tl][n2][r];
        dout[gbase + (((size_t)(n2 * 16 + 4 * hi + r)) << 14) + tokbase +
             tl * 16] = v;
      }
    }
  }
}

extern "C" void kernel_launch(void* const* d_in, const int* in_sizes, int n_in,
                              void* d_out, int out_size, void* d_ws, size_t ws_size,
                              hipStream_t stream) {
  (void)in_sizes; (void)n_in; (void)out_size; (void)ws_size;
  const float* x   = (const float*)d_in[0];
  const float* dww = (const float*)d_in[1];
  const float* dwb = (const float*)d_in[2];
  const float* pww = (const float*)d_in[3];
  const float* pwb = (const float*)d_in[4];
  const float* lnw = (const float*)d_in[5];
  const float* lnb = (const float*)d_in[6];
  const float* w1  = (const float*)d_in[7];
  const float* b1  = (const float*)d_in[8];
  const float* w2  = (const float*)d_in[9];
  const float* b2  = (const float*)d_in[10];
  float* out = (float*)d_out;

  float* scales = (float*)d_ws;
  unsigned* u1f = (unsigned*)((char*)d_ws + 16);
  unsigned* u2f = u1f + 4096;
  unsigned short* pwbf = (unsigned short*)((char*)d_ws + 16 + 32768);

  hipLaunchKernelGGL(k_prep, dim3(3), dim3(256), 0, stream,
                     w1, w2, pww, scales, u1f, u2f, pwbf);
  hipLaunchKernelGGL(k_dw, dim3(64, 64, 16), dim3(256), 0, stream,
                     x, dww, dwb, out);
  hipLaunchKernelGGL(k_fused, dim3(128, 16), dim3(256), 0, stream,
                     pwb, lnw, lnb, b1, b2, scales, u1f, u2f,
                     (const uint4*)pwbf, out);
}

// Round 7
// 200.596 us; speedup vs baseline: 2.6538x; 1.1364x over previous
//
#include <hip/hip_runtime.h>

#define DEVINL __device__ __forceinline__

typedef __attribute__((ext_vector_type(4))) int i32x4;
typedef __attribute__((ext_vector_type(4))) float f32x4;
typedef __attribute__((ext_vector_type(8))) __bf16 bf16x8;

DEVINL float rcp_nr(float x) {
  float r = __builtin_amdgcn_rcpf(x);
  return r * (2.0f - x * r);
}
DEVINL float rsq_nr(float x) {
  float r = __builtin_amdgcn_rsqf(x);
  return r * (1.5f - 0.5f * x * r * r);
}
// exact-GELU via Abramowitz-Stegun 7.1.26 erf (|abs err| < 1.5e-7), branchless
DEVINL float gelu_f(float x) {
  float z = fabsf(x) * 0.7071067811865476f;
  float t = rcp_nr(fmaf(0.3275911f, z, 1.0f));
  float p = fmaf(1.061405429f, t, -1.453152027f);
  p = fmaf(p, t, 1.421413741f);
  p = fmaf(p, t, -0.284496736f);
  p = fmaf(p, t, 0.254829592f);
  p = p * t;
  float er = fmaf(-p, __expf(-z * z), 1.0f);
  er = copysignf(er, x);
  return 0.5f * x * (1.0f + er);
}

DEVINL unsigned packq4(float a, float b, float c, float d, float scale) {
  int ia = (int)fminf(fmaxf(rintf(a * scale), -1.f), 1.f);
  int ib = (int)fminf(fmaxf(rintf(b * scale), -1.f), 1.f);
  int ic = (int)fminf(fmaxf(rintf(c * scale), -1.f), 1.f);
  int id = (int)fminf(fmaxf(rintf(d * scale), -1.f), 1.f);
  return (unsigned)(ia & 255) | ((unsigned)(ib & 255) << 8) |
         ((unsigned)(ic & 255) << 16) | ((unsigned)(id & 255) << 24);
}

DEVINL unsigned packq8(float a, float b, float c, float d, float s) {
  int q0 = (int)fminf(fmaxf(rintf(a * s), -128.f), 127.f);
  int q1 = (int)fminf(fmaxf(rintf(b * s), -128.f), 127.f);
  int q2 = (int)fminf(fmaxf(rintf(c * s), -128.f), 127.f);
  int q3 = (int)fminf(fmaxf(rintf(d * s), -128.f), 127.f);
  return (unsigned)(q0 & 255) | ((unsigned)(q1 & 255) << 8) |
         ((unsigned)(q2 & 255) << 16) | ((unsigned)(q3 & 255) << 24);
}

DEVINL long long mk64(unsigned lo, unsigned hi) {
  return (long long)(((unsigned long long)hi << 32) | (unsigned long long)lo);
}

// ------ kernel 0: ternary pack in MFMA-FRAG ORDER + pw bf16 hi/lo split -----
// (unchanged from r6 — layouts proven)
__global__ __launch_bounds__(256) void k_prep(
    const float* __restrict__ w1, const float* __restrict__ w2,
    const float* __restrict__ pww, float* __restrict__ scales,
    unsigned* __restrict__ u1f, unsigned* __restrict__ u2f,
    unsigned short* __restrict__ pwbf) {
  const int tid = threadIdx.x;
  const int bx = blockIdx.x;

  if (bx == 2) {
    for (int e = tid; e < 4096; e += 256) {
      int n2 = e >> 10, kh = (e >> 9) & 1, ln = (e >> 3) & 63, j = e & 7;
      int c = ln & 15, hh = ln >> 4;
      float v = pww[(n2 * 16 + c) * 64 + kh * 32 + hh * 8 + j];
      __bf16 hb = (__bf16)v;
      __bf16 lb = (__bf16)(v - (float)hb);
      pwbf[e] = __builtin_bit_cast(unsigned short, hb);
      pwbf[e + 4096] = __builtin_bit_cast(unsigned short, lb);
    }
    return;
  }

  __shared__ double red[4];
  __shared__ float mclip_s;
  const float* w = (bx == 0) ? w1 : w2;

  double s = 0.0;
  for (int e = tid; e < 16384; e += 256) s += (double)fabsf(w[e]);
  #pragma unroll
  for (int m = 32; m; m >>= 1) s += __shfl_xor(s, m, 64);
  if ((tid & 63) == 0) red[tid >> 6] = s;
  __syncthreads();
  if (tid == 0) {
    double tot = red[0] + red[1] + red[2] + red[3];
    float mc = fmaxf((float)(tot / 16384.0), 1e-5f);
    scales[bx] = mc;
    mclip_s = mc;
  }
  __syncthreads();
  const float scale = 1.0f / mclip_s;

  if (bx == 0) {
    for (int e = tid; e < 4096; e += 256) {
      int n = e >> 8, lane = (e >> 2) & 63, word = e & 3;
      int r = n * 16 + (lane & 15);
      int kdw = (word >> 1) * 8 + (lane >> 4) * 2 + (word & 1);
      const float* src = w1 + (r * 16 + kdw) * 4;
      u1f[e] = packq4(src[0], src[1], src[2], src[3], scale);
    }
  } else {
    for (int e = tid; e < 4096; e += 256) {
      int ks = e >> 9, n2 = (e >> 7) & 3, lane = (e >> 1) & 63, word = e & 1;
      int r = n2 * 16 + (lane & 15);
      int kdw = ks * 8 + (lane >> 4) * 2 + word;
      const float* src = w2 + (r * 64 + kdw) * 4;
      u2f[e] = packq4(src[0], src[1], src[2], src[3], scale);
    }
  }
}

// ---------------- kernel 1: depthwise 3x3 stencil (unchanged) ----------------
__global__ __launch_bounds__(256) void k_dw(
    const float* __restrict__ x, const float* __restrict__ dww,
    const float* __restrict__ dwb, float* __restrict__ dout) {
  const int tid = threadIdx.x;
  const int px = tid & 127, ry = tid >> 7;
  const int y = blockIdx.x * 2 + ry;
  const int c = blockIdx.y;
  const int bz = blockIdx.z;
  const float* xc = x + (((size_t)bz * 64 + c) << 14);

  float wv[9];
  #pragma unroll
  for (int i = 0; i < 9; ++i) wv[i] = dww[c * 9 + i];
  float acc = dwb[c];
  #pragma unroll
  for (int dy = 0; dy < 3; ++dy) {
    int iy = y + dy - 1;
    if ((unsigned)iy < 128u) {
      const float* row = xc + (iy << 7);
      #pragma unroll
      for (int dx = 0; dx < 3; ++dx) {
        int ix = px + dx - 1;
        if ((unsigned)ix < 128u) acc = fmaf(row[ix], wv[dy * 3 + dx], acc);
      }
    }
  }
  dout[(((size_t)bz * 64 + c) << 14) + (y << 7) + px] = acc;
}

// ------ kernel 2: cooperative-wave pw + LN + BitFF + residual ---------------
// Block = 4 waves = one image row (128 tokens), processed as 8 iterations of
// 16 tokens. ALL waves work on the SAME 16 tokens; wave w owns slice w:
//   pw/BL2 output channels w*16..w*16+15  (hacc[4]/c2 regs, residual in regs)
//   BL1 features         w*64..w*64+63   (g[4][4] = 16 regs)
// Cross-wave LN/rms reductions via tiny double-buffered LDS (5 barriers/iter,
// parity-safe). wq/qf2 are block-shared; every punned read (uint2/uint4 of
// unsigned-written LDS) is barrier-separated (r3/r6-proven discipline).
__global__ __launch_bounds__(256, 4) void k_fused(
    const float* __restrict__ pwb, const float* __restrict__ lnw,
    const float* __restrict__ lnb, const float* __restrict__ b1,
    const float* __restrict__ b2, const float* __restrict__ scales,
    const unsigned* __restrict__ u1f, const unsigned* __restrict__ u2f,
    const uint4* __restrict__ pwf, float* __restrict__ dout) {
  __shared__ __align__(16) unsigned w1f[4096];   // [n][lane] uint4 frags
  __shared__ __align__(16) unsigned w2f[4096];   // [ks][n2][lane] qword frags
  __shared__ __align__(16) unsigned wq[16 * 16]; // [tok][16 dw] int8 x
  __shared__ __align__(16) unsigned qf2[16 * 68];// [tok][68 dw] int8 gelu
  __shared__ float redA[2][4][16], redB[2][4][16];

  const int tid = threadIdx.x;
  const int w = tid >> 6, lane = tid & 63;
  const int col = lane & 15, hi = lane >> 4;
  const int y = blockIdx.x, bz = blockIdx.y;
  const size_t gbase = ((size_t)bz * 64) << 14;

  // ---- stage weights to LDS ----
  for (int e = tid; e < 4096; e += 256) w1f[e] = u1f[e];
  for (int e = tid; e < 4096; e += 256) w2f[e] = u2f[e];

  // ---- per-lane params (channel ch = w*16 + 4*hi + r) ----
  const int chb = w * 16 + 4 * hi;
  float pwbr[4], lnw_r[4], lnb_r[4], b2r[4];
  #pragma unroll
  for (int r = 0; r < 4; ++r) {
    pwbr[r] = pwb[chb + r];
    lnw_r[r] = lnw[chb + r];
    lnb_r[r] = lnb[chb + r];
    b2r[r] = b2[chb + r];
  }
  const float sc0 = scales[0], m2c = scales[1];

  // pw A-frags for this wave's n2 = w (held in 16 regs)
  uint4 pwa[2], pwl[2];
  #pragma unroll
  for (int kh = 0; kh < 2; ++kh) {
    pwa[kh] = pwf[(w * 2 + kh) * 64 + lane];
    pwl[kh] = pwf[(w * 2 + kh) * 64 + lane + 512];
  }
  __syncthreads();  // weights staged

  for (int it = 0; it < 8; ++it) {
    const int gcol = y * 128 + it * 16 + col;

    // ---- load h B-frag (16 scalar loads, 64B coalesced per hi-group) ----
    bf16x8 bh[2], bl[2];
    #pragma unroll
    for (int kh = 0; kh < 2; ++kh)
      #pragma unroll
      for (int j = 0; j < 8; ++j) {
        float v = dout[gbase + (((size_t)(kh * 32 + hi * 8 + j)) << 14) + gcol];
        __bf16 hb = (__bf16)v;
        bh[kh][j] = hb;
        bl[kh][j] = (__bf16)(v - (float)hb);
      }

    // ---- pw GEMM slice (bf16 hi/lo 3-term), out ch w*16+4hi+r ----
    f32x4 pacc = {0.f, 0.f, 0.f, 0.f};
    #pragma unroll
    for (int kh = 0; kh < 2; ++kh) {
      bf16x8 ah = __builtin_bit_cast(bf16x8, pwa[kh]);
      bf16x8 al = __builtin_bit_cast(bf16x8, pwl[kh]);
      pacc = __builtin_amdgcn_mfma_f32_16x16x32_bf16(ah, bh[kh], pacc, 0, 0, 0);
      pacc = __builtin_amdgcn_mfma_f32_16x16x32_bf16(ah, bl[kh], pacc, 0, 0, 0);
      pacc = __builtin_amdgcn_mfma_f32_16x16x32_bf16(al, bh[kh], pacc, 0, 0, 0);
    }
    float hacc[4];
    #pragma unroll
    for (int r = 0; r < 4; ++r) hacc[r] = pacc[r] + pwbr[r];

    // ---- S1: LN mean/var partials (4 ch) -> wave -> block ----
    float s1 = 0.f, q1 = 0.f;
    #pragma unroll
    for (int r = 0; r < 4; ++r) {
      s1 += hacc[r];
      q1 = fmaf(hacc[r], hacc[r], q1);
    }
    s1 += __shfl_xor(s1, 16, 64); s1 += __shfl_xor(s1, 32, 64);
    q1 += __shfl_xor(q1, 16, 64); q1 += __shfl_xor(q1, 32, 64);
    if (hi == 0) { redA[0][w][col] = s1; redB[0][w][col] = q1; }
    __syncthreads();  // B1
    float S = redA[0][0][col] + redA[0][1][col] + redA[0][2][col] + redA[0][3][col];
    float Q = redB[0][0][col] + redB[0][1][col] + redB[0][2][col] + redB[0][3][col];
    const float mu = S * (1.f / 64.f);
    const float var = fmaxf(Q * (1.f / 64.f) - mu * mu, 0.f);
    const float istd = rsq_nr(var + 1e-5f);

    // ---- tn + S2: rms1/amax partials ----
    float tn[4];
    float s2 = 0.f, am = 0.f;
    #pragma unroll
    for (int r = 0; r < 4; ++r) {
      float t = (hacc[r] - mu) * istd * lnw_r[r] + lnb_r[r];
      tn[r] = t;
      s2 = fmaf(t, t, s2);
      am = fmaxf(am, fabsf(t));
    }
    s2 += __shfl_xor(s2, 16, 64); s2 += __shfl_xor(s2, 32, 64);
    am = fmaxf(am, __shfl_xor(am, 16, 64));
    am = fmaxf(am, __shfl_xor(am, 32, 64));
    if (hi == 0) { redA[1][w][col] = s2; redB[1][w][col] = am; }
    __syncthreads();  // B2
    float S2 = redA[1][0][col] + redA[1][1][col] + redA[1][2][col] + redA[1][3][col];
    float AM = fmaxf(fmaxf(redB[1][0][col], redB[1][1][col]),
                     fmaxf(redB[1][2][col], redB[1][3][col]));

    const float n1 = sqrtf(S2);
    const float inv1 = rcp_nr(fmaxf(n1, 1e-12f));
    const float axc1 = fmaxf(AM * 8.f * inv1, 1e-5f);
    const float sx1 = 127.f * rcp_nr(axc1);
    const float qs1 = 8.f * inv1 * sx1;
    const float fsc1 = sc0 * axc1 * (1.f / 127.f);

    // ---- quantize x slice -> shared wq ----
    wq[col * 16 + w * 4 + hi] = packq8(tn[0], tn[1], tn[2], tn[3], qs1);
    __syncthreads();  // B3 (wq visible; also fences uint2 reads below)

    // ---- BitLinear1: features w*64..+63, interleaved dequant+GELU ----
    const uint2 bw0 = *(const uint2*)&wq[col * 16 + 2 * hi];
    const uint2 bw1 = *(const uint2*)&wq[col * 16 + 8 + 2 * hi];
    const long long bq0 = mk64(bw0.x, bw0.y);
    const long long bq1 = mk64(bw1.x, bw1.y);

    float g[4][4];
    float sum2 = 0.f, am2 = 0.f;
    #pragma unroll
    for (int n = 0; n < 4; ++n) {
      const uint4 wf = *(const uint4*)&w1f[(((w * 4 + n) * 64) + lane) * 4];
      i32x4 cc = {0, 0, 0, 0};
      cc = __builtin_amdgcn_mfma_i32_16x16x32_i8(mk64(wf.x, wf.y), bq0, cc, 0, 0, 0);
      cc = __builtin_amdgcn_mfma_i32_16x16x32_i8(mk64(wf.z, wf.w), bq1, cc, 0, 0, 0);
      const float4 bb = *(const float4*)&b1[w * 64 + n * 16 + 4 * hi];
      #pragma unroll
      for (int r = 0; r < 4; ++r) {
        float f = (float)cc[r] * fsc1 + ((const float*)&bb)[r];
        float gg = gelu_f(f);
        g[n][r] = gg;
        sum2 = fmaf(gg, gg, sum2);
        am2 = fmaxf(am2, fabsf(gg));
      }
    }
    sum2 += __shfl_xor(sum2, 16, 64); sum2 += __shfl_xor(sum2, 32, 64);
    am2 = fmaxf(am2, __shfl_xor(am2, 16, 64));
    am2 = fmaxf(am2, __shfl_xor(am2, 32, 64));
    if (hi == 0) { redA[0][w][col] = sum2; redB[0][w][col] = am2; }
    __syncthreads();  // B4
    float S4 = redA[0][0][col] + redA[0][1][col] + redA[0][2][col] + redA[0][3][col];
    float AM2 = fmaxf(fmaxf(redB[0][0][col], redB[0][1][col]),
                      fmaxf(redB[0][2][col], redB[0][3][col]));

    const float n2v = sqrtf(S4);
    const float inv2 = rcp_nr(fmaxf(n2v, 1e-12f));
    const float axc2 = fmaxf(AM2 * 16.f * inv2, 1e-5f);
    const float sx2 = 127.f * rcp_nr(axc2);
    const float qs2 = 16.f * inv2 * sx2;
    const float fsc2 = m2c * axc2 * (1.f / 127.f);

    // ---- quantize gelu slice -> shared qf2 ----
    #pragma unroll
    for (int n = 0; n < 4; ++n)
      qf2[col * 68 + w * 16 + n * 4 + hi] =
          packq8(g[n][0], g[n][1], g[n][2], g[n][3], qs2);
    __syncthreads();  // B5 (qf2 visible; fences uint2 reads below)

    // ---- BitLinear2: out ch w*16..+15, K=256 in 8 k-steps ----
    i32x4 c2 = {0, 0, 0, 0};
    #pragma unroll
    for (int ks = 0; ks < 8; ++ks) {
      const uint2 bw = *(const uint2*)&qf2[col * 68 + ks * 8 + 2 * hi];
      const long long bfr = mk64(bw.x, bw.y);
      const uint2 aw = *(const uint2*)&w2f[(((ks * 4 + w) * 64) + lane) * 2];
      const long long afr = mk64(aw.x, aw.y);
      c2 = __builtin_amdgcn_mfma_i32_16x16x32_i8(afr, bfr, c2, 0, 0, 0);
    }

    // ---- epilogue: dequant + b2 + residual (regs), store ----
    #pragma unroll
    for (int r = 0; r < 4; ++r) {
      float v = (float)c2[r] * fsc2 + b2r[r] + hacc[r];
      dout[gbase + (((size_t)(chb + r)) << 14) + gcol] = v;
    }
  }
}

extern "C" void kernel_launch(void* const* d_in, const int* in_sizes, int n_in,
                              void* d_out, int out_size, void* d_ws, size_t ws_size,
                              hipStream_t stream) {
  (void)in_sizes; (void)n_in; (void)out_size; (void)ws_size;
  const float* x   = (const float*)d_in[0];
  const float* dww = (const float*)d_in[1];
  const float* dwb = (const float*)d_in[2];
  const float* pww = (const float*)d_in[3];
  const float* pwb = (const float*)d_in[4];
  const float* lnw = (const float*)d_in[5];
  const float* lnb = (const float*)d_in[6];
  const float* w1  = (const float*)d_in[7];
  const float* b1  = (const float*)d_in[8];
  const float* w2  = (const float*)d_in[9];
  const float* b2  = (const float*)d_in[10];
  float* out = (float*)d_out;

  float* scales = (float*)d_ws;
  unsigned* u1f = (unsigned*)((char*)d_ws + 16);
  unsigned* u2f = u1f + 4096;
  unsigned short* pwbf = (unsigned short*)((char*)d_ws + 16 + 32768);

  hipLaunchKernelGGL(k_prep, dim3(3), dim3(256), 0, stream,
                     w1, w2, pww, scales, u1f, u2f, pwbf);
  hipLaunchKernelGGL(k_dw, dim3(64, 64, 16), dim3(256), 0, stream,
                     x, dww, dwb, out);
  hipLaunchKernelGGL(k_fused, dim3(128, 16), dim3(256), 0, stream,
                     pwb, lnw, lnb, b1, b2, scales, u1f, u2f,
                     (const uint4*)pwbf, out);
}

// Round 8
// 130.219 us; speedup vs baseline: 4.0881x; 1.5405x over previous
//
#include <hip/hip_runtime.h>

#define DEVINL __device__ __forceinline__

typedef __attribute__((ext_vector_type(4))) int i32x4;
typedef __attribute__((ext_vector_type(4))) float f32x4;
typedef __attribute__((ext_vector_type(8))) __bf16 bf16x8;

DEVINL float rcp_nr(float x) {
  float r = __builtin_amdgcn_rcpf(x);
  return r * (2.0f - x * r);
}
DEVINL float rsq_nr(float x) {
  float r = __builtin_amdgcn_rsqf(x);
  return r * (1.5f - 0.5f * x * r * r);
}
// exact-GELU via Abramowitz-Stegun 7.1.26 erf (|abs err| < 1.5e-7), branchless
DEVINL float gelu_f(float x) {
  float z = fabsf(x) * 0.7071067811865476f;
  float t = rcp_nr(fmaf(0.3275911f, z, 1.0f));
  float p = fmaf(1.061405429f, t, -1.453152027f);
  p = fmaf(p, t, 1.421413741f);
  p = fmaf(p, t, -0.284496736f);
  p = fmaf(p, t, 0.254829592f);
  p = p * t;
  float er = fmaf(-p, __expf(-z * z), 1.0f);
  er = copysignf(er, x);
  return 0.5f * x * (1.0f + er);
}

DEVINL unsigned packq4(float a, float b, float c, float d, float scale) {
  int ia = (int)fminf(fmaxf(rintf(a * scale), -1.f), 1.f);
  int ib = (int)fminf(fmaxf(rintf(b * scale), -1.f), 1.f);
  int ic = (int)fminf(fmaxf(rintf(c * scale), -1.f), 1.f);
  int id = (int)fminf(fmaxf(rintf(d * scale), -1.f), 1.f);
  return (unsigned)(ia & 255) | ((unsigned)(ib & 255) << 8) |
         ((unsigned)(ic & 255) << 16) | ((unsigned)(id & 255) << 24);
}

DEVINL unsigned packq8(float a, float b, float c, float d, float s) {
  int q0 = (int)fminf(fmaxf(rintf(a * s), -128.f), 127.f);
  int q1 = (int)fminf(fmaxf(rintf(b * s), -128.f), 127.f);
  int q2 = (int)fminf(fmaxf(rintf(c * s), -128.f), 127.f);
  int q3 = (int)fminf(fmaxf(rintf(d * s), -128.f), 127.f);
  return (unsigned)(q0 & 255) | ((unsigned)(q1 & 255) << 8) |
         ((unsigned)(q2 & 255) << 16) | ((unsigned)(q3 & 255) << 24);
}

DEVINL long long mk64(unsigned lo, unsigned hi) {
  return (long long)(((unsigned long long)hi << 32) | (unsigned long long)lo);
}

// ------ kernel 0: ternary pack in MFMA-FRAG ORDER + pw bf16 hi/lo split -----
// (unchanged from r6/r7 — layouts proven)
__global__ __launch_bounds__(256) void k_prep(
    const float* __restrict__ w1, const float* __restrict__ w2,
    const float* __restrict__ pww, float* __restrict__ scales,
    unsigned* __restrict__ u1f, unsigned* __restrict__ u2f,
    unsigned short* __restrict__ pwbf) {
  const int tid = threadIdx.x;
  const int bx = blockIdx.x;

  if (bx == 2) {
    for (int e = tid; e < 4096; e += 256) {
      int n2 = e >> 10, kh = (e >> 9) & 1, ln = (e >> 3) & 63, j = e & 7;
      int c = ln & 15, hh = ln >> 4;
      float v = pww[(n2 * 16 + c) * 64 + kh * 32 + hh * 8 + j];
      __bf16 hb = (__bf16)v;
      __bf16 lb = (__bf16)(v - (float)hb);
      pwbf[e] = __builtin_bit_cast(unsigned short, hb);
      pwbf[e + 4096] = __builtin_bit_cast(unsigned short, lb);
    }
    return;
  }

  __shared__ double red[4];
  __shared__ float mclip_s;
  const float* w = (bx == 0) ? w1 : w2;

  double s = 0.0;
  for (int e = tid; e < 16384; e += 256) s += (double)fabsf(w[e]);
  #pragma unroll
  for (int m = 32; m; m >>= 1) s += __shfl_xor(s, m, 64);
  if ((tid & 63) == 0) red[tid >> 6] = s;
  __syncthreads();
  if (tid == 0) {
    double tot = red[0] + red[1] + red[2] + red[3];
    float mc = fmaxf((float)(tot / 16384.0), 1e-5f);
    scales[bx] = mc;
    mclip_s = mc;
  }
  __syncthreads();
  const float scale = 1.0f / mclip_s;

  if (bx == 0) {
    for (int e = tid; e < 4096; e += 256) {
      int n = e >> 8, lane = (e >> 2) & 63, word = e & 3;
      int r = n * 16 + (lane & 15);
      int kdw = (word >> 1) * 8 + (lane >> 4) * 2 + (word & 1);
      const float* src = w1 + (r * 16 + kdw) * 4;
      u1f[e] = packq4(src[0], src[1], src[2], src[3], scale);
    }
  } else {
    for (int e = tid; e < 4096; e += 256) {
      int ks = e >> 9, n2 = (e >> 7) & 3, lane = (e >> 1) & 63, word = e & 1;
      int r = n2 * 16 + (lane & 15);
      int kdw = ks * 8 + (lane >> 4) * 2 + word;
      const float* src = w2 + (r * 64 + kdw) * 4;
      u2f[e] = packq4(src[0], src[1], src[2], src[3], scale);
    }
  }
}

// ---- kernel 1: depthwise 3x3, 4 outputs/thread, packed {bf16hi,bf16lo} ----
__global__ __launch_bounds__(256, 8) void k_dw(
    const float* __restrict__ x, const float* __restrict__ dww,
    const float* __restrict__ dwb, unsigned* __restrict__ hout) {
  const int tid = threadIdx.x;
  const int px = tid & 127, yq = tid >> 7;
  const int y0 = (blockIdx.x * 2 + yq) * 4;
  const int c = blockIdx.y, bz = blockIdx.z;
  const float* xc = x + (((size_t)bz * 64 + c) << 14);

  float wv[9];
  #pragma unroll
  for (int i = 0; i < 9; ++i) wv[i] = dww[c * 9 + i];
  const float bias = dwb[c];

  float v[6][3];
  #pragma unroll
  for (int ry = 0; ry < 6; ++ry) {
    int iy = y0 - 1 + ry;
    bool yok = (unsigned)iy < 128u;
    const float* row = xc + ((size_t)(iy & 127) << 7);
    #pragma unroll
    for (int dx = 0; dx < 3; ++dx) {
      int ix = px - 1 + dx;
      v[ry][dx] = (yok && (unsigned)ix < 128u) ? row[ix & 127] : 0.f;
    }
  }

  unsigned* op = hout + (((size_t)bz * 64 + c) << 14) + ((size_t)y0 << 7) + px;
  #pragma unroll
  for (int oy = 0; oy < 4; ++oy) {
    float acc = bias;
    #pragma unroll
    for (int ky = 0; ky < 3; ++ky)
      #pragma unroll
      for (int kx = 0; kx < 3; ++kx)
        acc = fmaf(v[oy + ky][kx], wv[ky * 3 + kx], acc);
    __bf16 hb = (__bf16)acc;
    __bf16 lb = (__bf16)(acc - (float)hb);
    op[(size_t)oy << 7] =
        ((unsigned)__builtin_bit_cast(unsigned short, hb) << 16) |
        (unsigned)__builtin_bit_cast(unsigned short, lb);
  }
}

// ------ kernel 2: cooperative-wave pw + LN + BitFF + residual ---------------
// r7 structure, with: ALL weights in registers (no w1f/w2f LDS), h read as
// packed {hi,lo} dwords unpacked via v_perm_b32, wq/qf2 rows padded to
// conflict-free even strides (18 / 70 dwords).
__global__ __launch_bounds__(256, 4) void k_fused(
    const float* __restrict__ pwb, const float* __restrict__ lnw,
    const float* __restrict__ lnb, const float* __restrict__ b1,
    const float* __restrict__ b2, const float* __restrict__ scales,
    const unsigned* __restrict__ u1f, const unsigned* __restrict__ u2f,
    const uint4* __restrict__ pwf, const unsigned* hpk, float* dout) {
  __shared__ __align__(16) unsigned wq[16 * 18];   // [tok][18 dw] int8 x
  __shared__ __align__(16) unsigned qf2[16 * 70];  // [tok][70 dw] int8 gelu
  __shared__ float redA[2][4][16], redB[2][4][16];

  const int tid = threadIdx.x;
  const int w = tid >> 6, lane = tid & 63;
  const int col = lane & 15, hi = lane >> 4;
  const int y = blockIdx.x, bz = blockIdx.y;
  const size_t gbase = ((size_t)bz * 64) << 14;

  // ---- per-lane params (channel ch = w*16 + 4*hi + r) ----
  const int chb = w * 16 + 4 * hi;
  float pwbr[4], lnw_r[4], lnb_r[4], b2r[4];
  #pragma unroll
  for (int r = 0; r < 4; ++r) {
    pwbr[r] = pwb[chb + r];
    lnw_r[r] = lnw[chb + r];
    lnb_r[r] = lnb[chb + r];
    b2r[r] = b2[chb + r];
  }
  const float sc0 = scales[0], m2c = scales[1];

  // ---- ALL weight fragments -> registers ----
  uint4 pwa[2], pwl[2];
  #pragma unroll
  for (int kh = 0; kh < 2; ++kh) {
    pwa[kh] = pwf[(w * 2 + kh) * 64 + lane];
    pwl[kh] = pwf[(w * 2 + kh) * 64 + lane + 512];
  }
  uint4 w1r[4];
  #pragma unroll
  for (int n = 0; n < 4; ++n)
    w1r[n] = *(const uint4*)&u1f[(((w * 4 + n) * 64) + lane) * 4];
  uint2 w2r[8];
  #pragma unroll
  for (int ks = 0; ks < 8; ++ks)
    w2r[ks] = *(const uint2*)&u2f[(((ks * 4 + w) * 64) + lane) * 2];

  #pragma unroll 1
  for (int it = 0; it < 8; ++it) {
    const int gcol = y * 128 + it * 16 + col;

    // ---- load packed h, build bf16 B-frags via byte-perm ----
    bf16x8 bh[2], bl[2];
    #pragma unroll
    for (int kh = 0; kh < 2; ++kh) {
      unsigned u[8];
      #pragma unroll
      for (int j = 0; j < 8; ++j)
        u[j] = hpk[gbase + (((size_t)(kh * 32 + hi * 8 + j)) << 14) + gcol];
      uint4 bhw, blw;
      #pragma unroll
      for (int jw = 0; jw < 4; ++jw) {
        ((unsigned*)&bhw)[jw] =
            __builtin_amdgcn_perm(u[2 * jw + 1], u[2 * jw], 0x07060302u);
        ((unsigned*)&blw)[jw] =
            __builtin_amdgcn_perm(u[2 * jw + 1], u[2 * jw], 0x05040100u);
      }
      bh[kh] = __builtin_bit_cast(bf16x8, bhw);
      bl[kh] = __builtin_bit_cast(bf16x8, blw);
    }

    // ---- pw GEMM slice (bf16 hi/lo 3-term), out ch w*16+4hi+r ----
    f32x4 pacc = {0.f, 0.f, 0.f, 0.f};
    #pragma unroll
    for (int kh = 0; kh < 2; ++kh) {
      bf16x8 ah = __builtin_bit_cast(bf16x8, pwa[kh]);
      bf16x8 al = __builtin_bit_cast(bf16x8, pwl[kh]);
      pacc = __builtin_amdgcn_mfma_f32_16x16x32_bf16(ah, bh[kh], pacc, 0, 0, 0);
      pacc = __builtin_amdgcn_mfma_f32_16x16x32_bf16(ah, bl[kh], pacc, 0, 0, 0);
      pacc = __builtin_amdgcn_mfma_f32_16x16x32_bf16(al, bh[kh], pacc, 0, 0, 0);
    }
    float hacc[4];
    #pragma unroll
    for (int r = 0; r < 4; ++r) hacc[r] = pacc[r] + pwbr[r];

    // ---- S1: LN mean/var partials -> wave -> block ----
    float s1 = 0.f, q1 = 0.f;
    #pragma unroll
    for (int r = 0; r < 4; ++r) {
      s1 += hacc[r];
      q1 = fmaf(hacc[r], hacc[r], q1);
    }
    s1 += __shfl_xor(s1, 16, 64); s1 += __shfl_xor(s1, 32, 64);
    q1 += __shfl_xor(q1, 16, 64); q1 += __shfl_xor(q1, 32, 64);
    if (hi == 0) { redA[0][w][col] = s1; redB[0][w][col] = q1; }
    __syncthreads();  // B1
    float S = redA[0][0][col] + redA[0][1][col] + redA[0][2][col] + redA[0][3][col];
    float Q = redB[0][0][col] + redB[0][1][col] + redB[0][2][col] + redB[0][3][col];
    const float mu = S * (1.f / 64.f);
    const float var = fmaxf(Q * (1.f / 64.f) - mu * mu, 0.f);
    const float istd = rsq_nr(var + 1e-5f);

    // ---- tn + S2: rms1/amax partials ----
    float tn[4];
    float s2 = 0.f, am = 0.f;
    #pragma unroll
    for (int r = 0; r < 4; ++r) {
      float t = (hacc[r] - mu) * istd * lnw_r[r] + lnb_r[r];
      tn[r] = t;
      s2 = fmaf(t, t, s2);
      am = fmaxf(am, fabsf(t));
    }
    s2 += __shfl_xor(s2, 16, 64); s2 += __shfl_xor(s2, 32, 64);
    am = fmaxf(am, __shfl_xor(am, 16, 64));
    am = fmaxf(am, __shfl_xor(am, 32, 64));
    if (hi == 0) { redA[1][w][col] = s2; redB[1][w][col] = am; }
    __syncthreads();  // B2
    float S2 = redA[1][0][col] + redA[1][1][col] + redA[1][2][col] + redA[1][3][col];
    float AM = fmaxf(fmaxf(redB[1][0][col], redB[1][1][col]),
                     fmaxf(redB[1][2][col], redB[1][3][col]));

    const float n1 = sqrtf(S2);
    const float inv1 = rcp_nr(fmaxf(n1, 1e-12f));
    const float axc1 = fmaxf(AM * 8.f * inv1, 1e-5f);
    const float sx1 = 127.f * rcp_nr(axc1);
    const float qs1 = 8.f * inv1 * sx1;
    const float fsc1 = sc0 * axc1 * (1.f / 127.f);

    // ---- quantize x slice -> shared wq (stride 18: conflict-free) ----
    wq[col * 18 + w * 4 + hi] = packq8(tn[0], tn[1], tn[2], tn[3], qs1);
    __syncthreads();  // B3 (wq visible; fences uint2 punned reads)

    // ---- BitLinear1: features w*64..+63, interleaved dequant+GELU ----
    const uint2 bw0 = *(const uint2*)&wq[col * 18 + 2 * hi];
    const uint2 bw1 = *(const uint2*)&wq[col * 18 + 8 + 2 * hi];
    const long long bq0 = mk64(bw0.x, bw0.y);
    const long long bq1 = mk64(bw1.x, bw1.y);

    float g[4][4];
    float sum2 = 0.f, am2 = 0.f;
    #pragma unroll
    for (int n = 0; n < 4; ++n) {
      i32x4 cc = {0, 0, 0, 0};
      cc = __builtin_amdgcn_mfma_i32_16x16x32_i8(mk64(w1r[n].x, w1r[n].y), bq0,
                                                 cc, 0, 0, 0);
      cc = __builtin_amdgcn_mfma_i32_16x16x32_i8(mk64(w1r[n].z, w1r[n].w), bq1,
                                                 cc, 0, 0, 0);
      const float4 bb = *(const float4*)&b1[w * 64 + n * 16 + 4 * hi];
      #pragma unroll
      for (int r = 0; r < 4; ++r) {
        float f = (float)cc[r] * fsc1 + ((const float*)&bb)[r];
        float gg = gelu_f(f);
        g[n][r] = gg;
        sum2 = fmaf(gg, gg, sum2);
        am2 = fmaxf(am2, fabsf(gg));
      }
    }
    sum2 += __shfl_xor(sum2, 16, 64); sum2 += __shfl_xor(sum2, 32, 64);
    am2 = fmaxf(am2, __shfl_xor(am2, 16, 64));
    am2 = fmaxf(am2, __shfl_xor(am2, 32, 64));
    if (hi == 0) { redA[0][w][col] = sum2; redB[0][w][col] = am2; }
    __syncthreads();  // B4
    float S4 = redA[0][0][col] + redA[0][1][col] + redA[0][2][col] + redA[0][3][col];
    float AM2 = fmaxf(fmaxf(redB[0][0][col], redB[0][1][col]),
                      fmaxf(redB[0][2][col], redB[0][3][col]));

    const float n2v = sqrtf(S4);
    const float inv2 = rcp_nr(fmaxf(n2v, 1e-12f));
    const float axc2 = fmaxf(AM2 * 16.f * inv2, 1e-5f);
    const float sx2 = 127.f * rcp_nr(axc2);
    const float qs2 = 16.f * inv2 * sx2;
    const float fsc2 = m2c * axc2 * (1.f / 127.f);

    // ---- quantize gelu slice -> shared qf2 (stride 70: conflict-free) ----
    #pragma unroll
    for (int n = 0; n < 4; ++n)
      qf2[col * 70 + w * 16 + n * 4 + hi] =
          packq8(g[n][0], g[n][1], g[n][2], g[n][3], qs2);
    __syncthreads();  // B5 (qf2 visible; fences uint2 punned reads)

    // ---- BitLinear2: out ch w*16..+15, K=256 in 8 k-steps ----
    i32x4 c2 = {0, 0, 0, 0};
    #pragma unroll
    for (int ks = 0; ks < 8; ++ks) {
      const uint2 bw = *(const uint2*)&qf2[col * 70 + ks * 8 + 2 * hi];
      const long long bfr = mk64(bw.x, bw.y);
      const long long afr = mk64(w2r[ks].x, w2r[ks].y);
      c2 = __builtin_amdgcn_mfma_i32_16x16x32_i8(afr, bfr, c2, 0, 0, 0);
    }

    // ---- epilogue: dequant + b2 + residual (regs), store ----
    #pragma unroll
    for (int r = 0; r < 4; ++r) {
      float v = (float)c2[r] * fsc2 + b2r[r] + hacc[r];
      dout[gbase + (((size_t)(chb + r)) << 14) + gcol] = v;
    }
  }
}

extern "C" void kernel_launch(void* const* d_in, const int* in_sizes, int n_in,
                              void* d_out, int out_size, void* d_ws, size_t ws_size,
                              hipStream_t stream) {
  (void)in_sizes; (void)n_in; (void)out_size; (void)ws_size;
  const float* x   = (const float*)d_in[0];
  const float* dww = (const float*)d_in[1];
  const float* dwb = (const float*)d_in[2];
  const float* pww = (const float*)d_in[3];
  const float* pwb = (const float*)d_in[4];
  const float* lnw = (const float*)d_in[5];
  const float* lnb = (const float*)d_in[6];
  const float* w1  = (const float*)d_in[7];
  const float* b1  = (const float*)d_in[8];
  const float* w2  = (const float*)d_in[9];
  const float* b2  = (const float*)d_in[10];
  float* out = (float*)d_out;

  float* scales = (float*)d_ws;
  unsigned* u1f = (unsigned*)((char*)d_ws + 16);
  unsigned* u2f = u1f + 4096;
  unsigned short* pwbf = (unsigned short*)((char*)d_ws + 16 + 32768);

  hipLaunchKernelGGL(k_prep, dim3(3), dim3(256), 0, stream,
                     w1, w2, pww, scales, u1f, u2f, pwbf);
  hipLaunchKernelGGL(k_dw, dim3(16, 64, 16), dim3(256), 0, stream,
                     x, dww, dwb, (unsigned*)out);
  hipLaunchKernelGGL(k_fused, dim3(128, 16), dim3(256), 0, stream,
                     pwb, lnw, lnb, b1, b2, scales, u1f, u2f,
                     (const uint4*)pwbf, (const unsigned*)out, out);
}